// Round 4
// baseline (2278.259 us; speedup 1.0000x reference)
//
#include <hip/hip_runtime.h>

#define NN 100000
#define EE 1600000
#define GG 1000
#define PERG 100
#define KK 30
#define HH 64

#define NB 782      // blocks/buckets of 128 dst nodes: 782*128 >= NN
#define CAP 4096    // max edges/bucket (mean 2048, sigma ~45 -> huge margin)
#define CHB 4096    // edges per bucket block -> 391 bucket blocks
#define BUCKET_BLOCKS ((EE + CHB - 1) / CHB)  // 391
#define PROJ_BLOCKS ((NN + 127) / 128)        // 782 == NB

// ---- bucket body: LDS histogram + per-(block,bucket) run reservation ----
__device__ __forceinline__ void bucket_body(int bid, float* smem,
                                            const int* __restrict__ src,
                                            const int* __restrict__ dst,
                                            int* __restrict__ gcur,
                                            int* __restrict__ pairs) {
  int* lhist = (int*)smem;
  int* lbase = lhist + NB;
  int* lcur = lbase + NB;
  const int t = threadIdx.x;
  const int c0 = bid * CHB;
  const int c1 = min(c0 + CHB, EE);
  for (int b = t; b < NB; b += 256) {
    lhist[b] = 0;
    lcur[b] = 0;
  }
  __syncthreads();
  for (int e = c0 + t; e < c1; e += 256) atomicAdd(&lhist[dst[e] >> 7], 1);
  __syncthreads();
  for (int b = t; b < NB; b += 256) {
    int c = lhist[b];
    lbase[b] = c ? atomicAdd(&gcur[b], c) : 0;
  }
  __syncthreads();
  for (int e = c0 + t; e < c1; e += 256) {
    int d = dst[e];
    int b = d >> 7;
    int p = atomicAdd(&lcur[b], 1);
    pairs[b * CAP + lbase[b] + p] = (src[e] << 7) | (d & 127);
  }
}

// ---- proj body: X [NN,K] @ (WL|WR) -> P, R. BM=128, 8x8 reg tile ----
template <int K>
__device__ __forceinline__ void proj_body(int bid, float* smem,
                                          const float* __restrict__ X,
                                          const float* __restrict__ WL,
                                          const float* __restrict__ WR,
                                          float* __restrict__ P,
                                          float* __restrict__ R) {
  constexpr int BM = 128, BK = 32, XSP = 40, WSP = 144;
  float* xs = smem;             // 128*40 floats
  float* ws = smem + BM * XSP;  // 32*144 floats
  const int t = threadIdx.x;
  const int row0 = bid * BM;
  const int tc = t & 15, tr = t >> 4;
  const int wcol = tc * 8 + (tc >> 2) * 4;

  float acc[8][8];
#pragma unroll
  for (int i = 0; i < 8; ++i)
#pragma unroll
    for (int j = 0; j < 8; ++j) acc[i][j] = 0.f;

  for (int k0 = 0; k0 < K; k0 += BK) {
    __syncthreads();
    for (int idx = t; idx < BM * 8; idx += 256) {
      int r = idx >> 3, c = idx & 7;
      int row = row0 + r;
      float4 v = make_float4(0.f, 0.f, 0.f, 0.f);
      if (row < NN) v = *reinterpret_cast<const float4*>(&X[(size_t)row * K + k0 + c * 4]);
      *reinterpret_cast<float4*>(&xs[r * XSP + c * 4]) = v;
    }
    for (int idx = t; idx < BK * 16; idx += 256) {
      int kr = idx >> 4, c4 = idx & 15;
      int gcl = c4 >> 1;
      int off = gcl * 8 + (gcl >> 2) * 4 + (c4 & 1) * 4;
      *reinterpret_cast<float4*>(&ws[kr * WSP + off]) =
          *reinterpret_cast<const float4*>(&WL[(k0 + kr) * 64 + c4 * 4]);
      int g2 = gcl + 8;
      int off2 = g2 * 8 + (g2 >> 2) * 4 + (c4 & 1) * 4;
      *reinterpret_cast<float4*>(&ws[kr * WSP + off2]) =
          *reinterpret_cast<const float4*>(&WR[(k0 + kr) * 64 + c4 * 4]);
    }
    __syncthreads();
    for (int kk4 = 0; kk4 < BK; kk4 += 4) {
      float4 a[8];
#pragma unroll
      for (int i = 0; i < 8; ++i)
        a[i] = *reinterpret_cast<const float4*>(&xs[(tr + 16 * i) * XSP + kk4]);
#pragma unroll
      for (int kk = 0; kk < 4; ++kk) {
        float4 b0 = *reinterpret_cast<const float4*>(&ws[(kk4 + kk) * WSP + wcol]);
        float4 b1 = *reinterpret_cast<const float4*>(&ws[(kk4 + kk) * WSP + wcol + 4]);
        float bv[8] = {b0.x, b0.y, b0.z, b0.w, b1.x, b1.y, b1.z, b1.w};
#pragma unroll
        for (int i = 0; i < 8; ++i) {
          float av = (kk == 0) ? a[i].x : (kk == 1) ? a[i].y : (kk == 2) ? a[i].z : a[i].w;
#pragma unroll
          for (int j = 0; j < 8; ++j) acc[i][j] = fmaf(av, bv[j], acc[i][j]);
        }
      }
    }
  }

  float* OUT = (tc < 8) ? P : R;
  int cb = (tc & 7) * 8;
#pragma unroll
  for (int i = 0; i < 8; ++i) {
    int row = row0 + tr + 16 * i;
    if (row < NN) {
      *reinterpret_cast<float4*>(&OUT[(size_t)row * 64 + cb]) =
          make_float4(acc[i][0], acc[i][1], acc[i][2], acc[i][3]);
      *reinterpret_cast<float4*>(&OUT[(size_t)row * 64 + cb + 4]) =
          make_float4(acc[i][4], acc[i][5], acc[i][6], acc[i][7]);
    }
  }
}

// Heterogeneous launch: proj blocks first (all resident), buckets backfill.
__global__ __launch_bounds__(256) void fused_bucket_proj(const int* __restrict__ src,
                                                         const int* __restrict__ dst,
                                                         int* __restrict__ gcur,
                                                         int* __restrict__ pairs,
                                                         const float* __restrict__ X,
                                                         const float* __restrict__ WL,
                                                         const float* __restrict__ WR,
                                                         float* __restrict__ P,
                                                         float* __restrict__ R) {
  __shared__ float smem[128 * 40 + 32 * 144];  // 38912 B, covers both roles
  if (blockIdx.x < PROJ_BLOCKS)
    proj_body<128>(blockIdx.x, smem, X, WL, WR, P, R);
  else
    bucket_body(blockIdx.x - PROJ_BLOCKS, smem, src, dst, gcur, pairs);
}

// csr v2: per block, 13-bin counting sort of its edge run by src-slice
// (slice = src>>13, 8192 nodes = 2 MB of P per slice < 4 MB L2/XCD) and emit
// per-node degree. No inter-block prefix scan, no per-node CSR needed.
__global__ __launch_bounds__(256) void csr_kernel(const int* __restrict__ gcur,
                                                  const int* __restrict__ pairs,
                                                  int* __restrict__ cnt,
                                                  int* __restrict__ elist) {
  __shared__ int vals[CAP];
  __shared__ int hd[128];
  __shared__ int hsl[16];
  __shared__ int csl[16];
  const int b = blockIdx.x;
  const int t = threadIdx.x;
  if (t < 128) hd[t] = 0;
  if (t < 16) {
    hsl[t] = 0;
    csl[t] = 0;
  }
  __syncthreads();
  const int nb = gcur[b];
  for (int i = t; i < nb; i += 256) {
    int v = pairs[b * CAP + i];
    vals[i] = v;
    atomicAdd(&hd[v & 127], 1);
    atomicAdd(&hsl[v >> 20], 1);  // v>>20 == src>>13, v < 2^24
  }
  __syncthreads();
  if (t < 128) {
    int node = b * 128 + t;
    if (node < NN) cnt[node] = hd[t];
  }
  if (t == 0) {
    int run = 0;
#pragma unroll
    for (int s = 0; s < 16; ++s) {
      int c = hsl[s];
      hsl[s] = run;
      run += c;
    }
  }
  __syncthreads();
  for (int i = t; i < nb; i += 256) {
    int v = vals[i];
    int s = v >> 20;
    int p = atomicAdd(&csl[s], 1);
    elist[b * CAP + hsl[s] + p] = v;
  }
}

// ---- layer v2: edge-major slice-phased gather into LDS msum + fused GEMM ----
// Block b owns dst nodes [b*128, b*128+128) and its slice-sorted edge list.
// Quarter-wave per edge; lane ql covers floats ql*4..ql*4+3; accumulate via
// LDS float atomics. All blocks walk their lists in the same slice order ->
// instantaneous gather working set ~2 MB -> L2-resident.
// FINAL=false: finalize (mean+bias+self+relu) in LDS, then GEMM -> Pout/Rout.
// FINAL=true:  finalize straight to global h (Pout) + keys; no GEMM.
template <bool FINAL>
__global__ __launch_bounds__(256) void layer2_kernel(const float* __restrict__ P,
                                                     const float* __restrict__ R,
                                                     const float* __restrict__ bias,
                                                     const int* __restrict__ cnt,
                                                     const int* __restrict__ gcur,
                                                     const int* __restrict__ elist,
                                                     const float* __restrict__ WL,
                                                     const float* __restrict__ WR,
                                                     float* __restrict__ Pout,
                                                     float* __restrict__ Rout,
                                                     float* __restrict__ keys) {
  __shared__ float ms[128 * 68];  // 34816 B -> 4 blocks/CU
  const int t = threadIdx.x;
  const int b = blockIdx.x;
  const int row0 = b * 128;
  for (int i = t; i < 128 * 68; i += 256) ms[i] = 0.f;
  __syncthreads();

  const int qe = t >> 4;  // edge slot 0..15
  const int ql = t & 15;  // feature quarter
  const int nb = gcur[b];
  const int ebase = b * CAP;
  for (int e = qe; e < nb; e += 16) {
    const int v = elist[ebase + e];  // uniform within quarter (broadcast)
    const int sj = v >> 7;
    const int ld = v & 127;
    const float4 p4 = *reinterpret_cast<const float4*>(&P[(size_t)sj * 64 + ql * 4]);
    float* mrow = &ms[ld * 68 + ql * 4];
    atomicAdd(mrow + 0, p4.x);
    atomicAdd(mrow + 1, p4.y);
    atomicAdd(mrow + 2, p4.z);
    atomicAdd(mrow + 3, p4.w);
  }
  __syncthreads();

  // finalize: mean + bias + self + relu, in place (and to global if FINAL)
  for (int idx = t; idx < 128 * 16; idx += 256) {
    const int r = idx >> 4, c4 = idx & 15;
    const int node = row0 + r;
    if (node < NN) {
      float4 m = *reinterpret_cast<float4*>(&ms[r * 68 + c4 * 4]);
      const float dv = fmaxf((float)cnt[node], 1.f);
      const float4 r4 = *reinterpret_cast<const float4*>(&R[(size_t)node * 64 + c4 * 4]);
      const float4 b4 = *reinterpret_cast<const float4*>(&bias[c4 * 4]);
      float4 o;
      o.x = fmaxf(m.x / dv + b4.x + r4.x, 0.f);
      o.y = fmaxf(m.y / dv + b4.y + r4.y, 0.f);
      o.z = fmaxf(m.z / dv + b4.z + r4.z, 0.f);
      o.w = fmaxf(m.w / dv + b4.w + r4.w, 0.f);
      *reinterpret_cast<float4*>(&ms[r * 68 + c4 * 4]) = o;
      if (FINAL) {
        *reinterpret_cast<float4*>(&Pout[(size_t)node * 64 + c4 * 4]) = o;
        if (c4 == 15) keys[node] = o.w;  // feature 63
      }
    }
  }
  if (FINAL) return;
  __syncthreads();

  // GEMM: ms[128x64] @ (WL|WR)[64x64] -> Pout/Rout; W from global (L1 bcast).
  const int tc = t & 15, tr = t >> 4;
  const float* WB = (tc < 8) ? WL : WR;
  const int wcolg = (tc & 7) * 8;

  float acc[8][8];
#pragma unroll
  for (int i = 0; i < 8; ++i)
#pragma unroll
    for (int j = 0; j < 8; ++j) acc[i][j] = 0.f;

  for (int kk4 = 0; kk4 < 64; kk4 += 4) {
    float4 a[8];
#pragma unroll
    for (int i = 0; i < 8; ++i)
      a[i] = *reinterpret_cast<const float4*>(&ms[(tr + 16 * i) * 68 + kk4]);
#pragma unroll
    for (int kk = 0; kk < 4; ++kk) {
      float4 b0 = *reinterpret_cast<const float4*>(&WB[(kk4 + kk) * 64 + wcolg]);
      float4 b1 = *reinterpret_cast<const float4*>(&WB[(kk4 + kk) * 64 + wcolg + 4]);
      float bv[8] = {b0.x, b0.y, b0.z, b0.w, b1.x, b1.y, b1.z, b1.w};
#pragma unroll
      for (int i = 0; i < 8; ++i) {
        float av = (kk == 0) ? a[i].x : (kk == 1) ? a[i].y : (kk == 2) ? a[i].z : a[i].w;
#pragma unroll
        for (int j = 0; j < 8; ++j) acc[i][j] = fmaf(av, bv[j], acc[i][j]);
      }
    }
  }

  float* OUT = (tc < 8) ? Pout : Rout;
  const int cb = (tc & 7) * 8;
#pragma unroll
  for (int i = 0; i < 8; ++i) {
    int row = row0 + tr + 16 * i;
    if (row < NN) {
      *reinterpret_cast<float4*>(&OUT[(size_t)row * 64 + cb]) =
          make_float4(acc[i][0], acc[i][1], acc[i][2], acc[i][3]);
      *reinterpret_cast<float4*>(&OUT[(size_t)row * 64 + cb + 4]) =
          make_float4(acc[i][4], acc[i][5], acc[i][6], acc[i][7]);
    }
  }
}

// one block (256 thr) per graph: stable top-30, conv1d, MLP head.
__global__ __launch_bounds__(256) void head_kernel(const float* __restrict__ h,
                                                   const float* __restrict__ keysArr,
                                                   const float* __restrict__ cw,
                                                   const float* __restrict__ cb,
                                                   const float* __restrict__ w1,
                                                   const float* __restrict__ bb1,
                                                   const float* __restrict__ w2,
                                                   const float* __restrict__ bb2,
                                                   float* __restrict__ out) {
  __shared__ float key[PERG];
  __shared__ int sel[KK];
  __shared__ float feat[34 * 65];
  __shared__ float cwT[192 * 33];
  __shared__ float z[896];
  __shared__ float psum[256];
  const int g = blockIdx.x;
  const int t = threadIdx.x;

  for (int idx = t; idx < 32 * 192; idx += 256) {
    int o = idx / 192, k = idx % 192;
    cwT[k * 33 + o] = cw[idx];
  }
  if (t < PERG) key[t] = keysArr[g * PERG + t];
  __syncthreads();

  if (t < PERG) {
    float kv = key[t];
    int r = 0;
    for (int m = 0; m < PERG; ++m) {
      float km = key[m];
      r += (int)((km > kv) || (km == kv && m < t));
    }
    if (r < KK) sel[r] = t;
  }
  __syncthreads();

  for (int idx = t; idx < KK * HH; idx += 256) {
    int r = idx >> 6, f = idx & 63;
    feat[r * 65 + f] = h[(size_t)(g * PERG + sel[r]) * HH + f];
  }
  __syncthreads();

  {
    const int o = t & 31;
    const int pg = t >> 5;
    float zacc[4] = {0.f, 0.f, 0.f, 0.f};
    int i = 0, tt = 0;
    for (int k = 0; k < 192; ++k) {
      float c = cwT[k * 33 + o];
#pragma unroll
      for (int j = 0; j < 4; ++j) {
        int p = pg + 8 * j;
        zacc[j] = fmaf(c, feat[(p + tt) * 65 + i], zacc[j]);
      }
      if (++tt == 3) {
        tt = 0;
        ++i;
      }
    }
    float cbo = cb[o];
#pragma unroll
    for (int j = 0; j < 4; ++j) {
      int p = pg + 8 * j;
      if (p < 28) z[o * 28 + p] = fmaxf(zacc[j] + cbo, 0.f);
    }
  }
  __syncthreads();

  {
    const int hh = t & 63;
    const int quarter = t >> 6;
    const int q0 = quarter * 224;
    float acc = 0.f;
    for (int q = 0; q < 224; ++q)
      acc = fmaf(z[q0 + q], w1[(size_t)(q0 + q) * 64 + hh], acc);
    psum[t] = acc;
  }
  __syncthreads();

  if (t < 64) {
    float o1 = fmaxf(bb1[t] + psum[t] + psum[t + 64] + psum[t + 128] + psum[t + 192], 0.f);
    float v = o1 * w2[t];
#pragma unroll
    for (int off = 32; off > 0; off >>= 1) v += __shfl_down(v, off);
    if (t == 0) out[g] = v + bb2[0];
  }
}

extern "C" void kernel_launch(void* const* d_in, const int* in_sizes, int n_in,
                              void* d_out, int out_size, void* d_ws, size_t ws_size,
                              hipStream_t stream) {
  const float* x = (const float*)d_in[0];
  const int* src = (const int*)d_in[1];
  const int* dst = (const int*)d_in[2];
  const float* wl1 = (const float*)d_in[4];
  const float* wr1 = (const float*)d_in[5];
  const float* b1 = (const float*)d_in[6];
  const float* wl2 = (const float*)d_in[7];
  const float* wr2 = (const float*)d_in[8];
  const float* b2 = (const float*)d_in[9];
  const float* wl3 = (const float*)d_in[10];
  const float* wr3 = (const float*)d_in[11];
  const float* b3 = (const float*)d_in[12];
  const float* cw = (const float*)d_in[13];
  const float* cb = (const float*)d_in[14];
  const float* w1 = (const float*)d_in[15];
  const float* bb1 = (const float*)d_in[16];
  const float* w2 = (const float*)d_in[17];
  const float* bb2 = (const float*)d_in[18];
  float* out = (float*)d_out;

  char* w = (char*)d_ws;
  auto carve = [&](size_t bytes) {
    char* p = w;
    w += (bytes + 255) & ~(size_t)255;
    return p;
  };
  int* cnt = (int*)carve((size_t)NN * 4);
  int* elist = (int*)carve((size_t)NB * CAP * 4);  // slice-sorted per-block edges
  float* P = (float*)carve((size_t)NN * 64 * 4);
  float* R = (float*)carve((size_t)NN * 64 * 4);
  float* hbuf = (float*)carve((size_t)NN * 64 * 4);
  float* R2 = (float*)carve((size_t)NN * 64 * 4);
  float* keys = (float*)carve((size_t)NN * 4);
  int* gcur = (int*)carve((size_t)NB * 4);
  // pairs aliases hbuf: csr reads pairs before layer1 writes P2=hbuf.
  int* pairs = (int*)hbuf;
  float* P2 = hbuf;

  hipMemsetAsync(gcur, 0, (size_t)NB * 4, stream);
  fused_bucket_proj<<<BUCKET_BLOCKS + PROJ_BLOCKS, 256, 0, stream>>>(
      src, dst, gcur, pairs, x, wl1, wr1, P, R);
  csr_kernel<<<NB, 256, 0, stream>>>(gcur, pairs, cnt, elist);

  // layer1: agg(P,R,b1) -> LDS -> P2,R2 = h1 @ (wl2|wr2)
  layer2_kernel<false><<<NB, 256, 0, stream>>>(P, R, b1, cnt, gcur, elist,
                                               wl2, wr2, P2, R2, nullptr);
  // layer2: agg(P2,R2,b2) -> LDS -> P,R = h2 @ (wl3|wr3)
  layer2_kernel<false><<<NB, 256, 0, stream>>>(P2, R2, b2, cnt, gcur, elist,
                                               wl3, wr3, P, R, nullptr);
  // layer3 (final): agg(P,R,b3) -> h (hbuf) + keys
  layer2_kernel<true><<<NB, 256, 0, stream>>>(P, R, b3, cnt, gcur, elist,
                                              nullptr, nullptr, hbuf, nullptr, keys);
  head_kernel<<<GG, 256, 0, stream>>>(hbuf, keys, cw, cb, w1, bb1, w2, bb2, out);
}

// Round 5
// 510.696 us; speedup vs baseline: 4.4611x; 4.4611x over previous
//
#include <hip/hip_runtime.h>

#define NN 100000
#define EE 1600000
#define GG 1000
#define PERG 100
#define KK 30
#define HH 64

#define NB 782      // buckets of 128 nodes: 782*128 = 100096 >= NN
#define CAP 4096    // max edges/bucket (mean 2048, sigma ~45 -> huge margin)
#define CHB 4096    // edges per bucket block -> 391 bucket blocks
#define BUCKET_BLOCKS ((EE + CHB - 1) / CHB)  // 391
#define PROJ_BLOCKS ((NN + 127) / 128)        // 782
#define LAYER_BLOCKS PROJ_BLOCKS

// ---- bucket body: LDS histogram + per-(block,bucket) run reservation ----
__device__ __forceinline__ void bucket_body(int bid, float* smem,
                                            const int* __restrict__ src,
                                            const int* __restrict__ dst,
                                            int* __restrict__ gcur,
                                            int* __restrict__ pairs) {
  int* lhist = (int*)smem;
  int* lbase = lhist + NB;
  int* lcur = lbase + NB;
  const int t = threadIdx.x;
  const int c0 = bid * CHB;
  const int c1 = min(c0 + CHB, EE);
  for (int b = t; b < NB; b += 256) {
    lhist[b] = 0;
    lcur[b] = 0;
  }
  __syncthreads();
  for (int e = c0 + t; e < c1; e += 256) atomicAdd(&lhist[dst[e] >> 7], 1);
  __syncthreads();
  for (int b = t; b < NB; b += 256) {
    int c = lhist[b];
    lbase[b] = c ? atomicAdd(&gcur[b], c) : 0;
  }
  __syncthreads();
  for (int e = c0 + t; e < c1; e += 256) {
    int d = dst[e];
    int b = d >> 7;
    int p = atomicAdd(&lcur[b], 1);
    pairs[b * CAP + lbase[b] + p] = (src[e] << 7) | (d & 127);
  }
}

// ---- proj body: X [NN,K] @ (WL|WR) -> P, R. BM=128, 8x8 reg tile ----
template <int K>
__device__ __forceinline__ void proj_body(int bid, float* smem,
                                          const float* __restrict__ X,
                                          const float* __restrict__ WL,
                                          const float* __restrict__ WR,
                                          float* __restrict__ P,
                                          float* __restrict__ R) {
  constexpr int BM = 128, BK = 32, XSP = 40, WSP = 144;
  float* xs = smem;             // 128*40 floats
  float* ws = smem + BM * XSP;  // 32*144 floats
  const int t = threadIdx.x;
  const int row0 = bid * BM;
  const int tc = t & 15, tr = t >> 4;
  const int wcol = tc * 8 + (tc >> 2) * 4;

  float acc[8][8];
#pragma unroll
  for (int i = 0; i < 8; ++i)
#pragma unroll
    for (int j = 0; j < 8; ++j) acc[i][j] = 0.f;

  for (int k0 = 0; k0 < K; k0 += BK) {
    __syncthreads();
    for (int idx = t; idx < BM * 8; idx += 256) {
      int r = idx >> 3, c = idx & 7;
      int row = row0 + r;
      float4 v = make_float4(0.f, 0.f, 0.f, 0.f);
      if (row < NN) v = *reinterpret_cast<const float4*>(&X[(size_t)row * K + k0 + c * 4]);
      *reinterpret_cast<float4*>(&xs[r * XSP + c * 4]) = v;
    }
    for (int idx = t; idx < BK * 16; idx += 256) {
      int kr = idx >> 4, c4 = idx & 15;
      int gcl = c4 >> 1;
      int off = gcl * 8 + (gcl >> 2) * 4 + (c4 & 1) * 4;
      *reinterpret_cast<float4*>(&ws[kr * WSP + off]) =
          *reinterpret_cast<const float4*>(&WL[(k0 + kr) * 64 + c4 * 4]);
      int g2 = gcl + 8;
      int off2 = g2 * 8 + (g2 >> 2) * 4 + (c4 & 1) * 4;
      *reinterpret_cast<float4*>(&ws[kr * WSP + off2]) =
          *reinterpret_cast<const float4*>(&WR[(k0 + kr) * 64 + c4 * 4]);
    }
    __syncthreads();
    for (int kk4 = 0; kk4 < BK; kk4 += 4) {
      float4 a[8];
#pragma unroll
      for (int i = 0; i < 8; ++i)
        a[i] = *reinterpret_cast<const float4*>(&xs[(tr + 16 * i) * XSP + kk4]);
#pragma unroll
      for (int kk = 0; kk < 4; ++kk) {
        float4 b0 = *reinterpret_cast<const float4*>(&ws[(kk4 + kk) * WSP + wcol]);
        float4 b1 = *reinterpret_cast<const float4*>(&ws[(kk4 + kk) * WSP + wcol + 4]);
        float bv[8] = {b0.x, b0.y, b0.z, b0.w, b1.x, b1.y, b1.z, b1.w};
#pragma unroll
        for (int i = 0; i < 8; ++i) {
          float av = (kk == 0) ? a[i].x : (kk == 1) ? a[i].y : (kk == 2) ? a[i].z : a[i].w;
#pragma unroll
          for (int j = 0; j < 8; ++j) acc[i][j] = fmaf(av, bv[j], acc[i][j]);
        }
      }
    }
  }

  float* OUT = (tc < 8) ? P : R;
  int cb = (tc & 7) * 8;
#pragma unroll
  for (int i = 0; i < 8; ++i) {
    int row = row0 + tr + 16 * i;
    if (row < NN) {
      *reinterpret_cast<float4*>(&OUT[(size_t)row * 64 + cb]) =
          make_float4(acc[i][0], acc[i][1], acc[i][2], acc[i][3]);
      *reinterpret_cast<float4*>(&OUT[(size_t)row * 64 + cb + 4]) =
          make_float4(acc[i][4], acc[i][5], acc[i][6], acc[i][7]);
    }
  }
}

// Heterogeneous launch: proj blocks first (all resident), buckets backfill.
__global__ __launch_bounds__(256) void fused_bucket_proj(const int* __restrict__ src,
                                                         const int* __restrict__ dst,
                                                         int* __restrict__ gcur,
                                                         int* __restrict__ pairs,
                                                         const float* __restrict__ X,
                                                         const float* __restrict__ WL,
                                                         const float* __restrict__ WR,
                                                         float* __restrict__ P,
                                                         float* __restrict__ R) {
  __shared__ float smem[128 * 40 + 32 * 144];  // 38912 B, covers both roles
  if (blockIdx.x < PROJ_BLOCKS)
    proj_body<128>(blockIdx.x, smem, X, WL, WR, P, R);
  else
    bucket_body(blockIdx.x - PROJ_BLOCKS, smem, src, dst, gcur, pairs);
}

// Phase C with inline scan: block b computes base = sum(gcur[0..b)) itself
// (<=782 L2-cached ints), then 128-bin LDS counting sort -> row_start/cnt/eidx.
__global__ __launch_bounds__(256) void csr_kernel(const int* __restrict__ gcur,
                                                  const int* __restrict__ pairs,
                                                  int* __restrict__ row_start,
                                                  int* __restrict__ cnt,
                                                  int* __restrict__ eidx) {
  __shared__ int vals[CAP];
  __shared__ int hist[128];
  __shared__ int offs[128];
  __shared__ int cur[128];
  __shared__ int red[4];
  const int b = blockIdx.x;
  const int t = threadIdx.x;
  int s = 0;
  for (int i = t; i < b; i += 256) s += gcur[i];
#pragma unroll
  for (int off = 32; off > 0; off >>= 1) s += __shfl_xor(s, off);
  if ((t & 63) == 0) red[t >> 6] = s;
  if (t < 128) {
    hist[t] = 0;
    cur[t] = 0;
  }
  __syncthreads();
  const int base = red[0] + red[1] + red[2] + red[3];
  const int nb = gcur[b];
  for (int i = t; i < nb; i += 256) {
    int v = pairs[b * CAP + i];
    vals[i] = v;
    atomicAdd(&hist[v & 127], 1);
  }
  __syncthreads();
  if (t < 128) {
    int ss = 0;
    for (int m = 0; m < t; ++m) ss += hist[m];
    offs[t] = ss;
    int node = b * 128 + t;
    if (node < NN) {
      row_start[node] = base + ss;
      cnt[node] = hist[t];
    }
  }
  __syncthreads();
  for (int i = t; i < nb; i += 256) {
    int v = vals[i];
    int ld = v & 127;
    int p = atomicAdd(&cur[ld], 1);
    eidx[base + offs[ld] + p] = v >> 7;
  }
}

// agg v3: quarter per TWO nodes (A at nodeBase+q, B at +4), lane = feature
// quarter. 32 gathers in flight per lane-chain (2x v2) to amortize the
// eidx/row_start load latency against the P-gather latency.
__global__ __launch_bounds__(256) void agg_kernel(const float* __restrict__ P,
                                                  const float* __restrict__ R,
                                                  const float* __restrict__ bias,
                                                  const int* __restrict__ row_start,
                                                  const int* __restrict__ cnt,
                                                  const int* __restrict__ eidx,
                                                  float* __restrict__ h,
                                                  float* __restrict__ keys) {
  const int wv = (blockIdx.x * 256 + threadIdx.x) >> 6;  // wave id
  const int lane = threadIdx.x & 63;
  const int q = lane >> 4;   // quarter id
  const int ql = lane & 15;  // feature quarter
  const int nodeA = wv * 8 + q;
  const int nodeB = nodeA + 4;
  const bool okA = (nodeA < NN), okB = (nodeB < NN);
  if (!okA) return;  // nodeA >= NN implies nodeB too (wave-uniform-ish exit ok)
  const int degA = cnt[nodeA];
  const int degB = okB ? cnt[nodeB] : 0;
  const int baseA = row_start[nodeA];
  const int baseB = okB ? row_start[nodeB] : 0;
  float4 accA = make_float4(0.f, 0.f, 0.f, 0.f);
  float4 accB = make_float4(0.f, 0.f, 0.f, 0.f);

  const int mx = max(degA, degB);
  for (int e0 = 0; e0 < mx; e0 += 16) {
    const int remA = degA - e0;
    const int remB = degB - e0;
    const int iiA = min(ql, max(remA - 1, 0));
    const int iiB = min(ql, max(remB - 1, 0));
    const int idxA = (remA > 0) ? eidx[baseA + e0 + iiA] : 0;
    const int idxB = (remB > 0) ? eidx[baseB + e0 + iiB] : 0;
#pragma unroll
    for (int j = 0; j < 16; ++j) {
      const int sA = __shfl(idxA, (lane & 48) | j);
      const int sB = __shfl(idxB, (lane & 48) | j);
      const float wA = (j < remA) ? 1.f : 0.f;
      const float wB = (j < remB) ? 1.f : 0.f;
      const float4 vA = *reinterpret_cast<const float4*>(&P[(size_t)sA * 64 + ql * 4]);
      const float4 vB = *reinterpret_cast<const float4*>(&P[(size_t)sB * 64 + ql * 4]);
      accA.x = fmaf(wA, vA.x, accA.x); accA.y = fmaf(wA, vA.y, accA.y);
      accA.z = fmaf(wA, vA.z, accA.z); accA.w = fmaf(wA, vA.w, accA.w);
      accB.x = fmaf(wB, vB.x, accB.x); accB.y = fmaf(wB, vB.y, accB.y);
      accB.z = fmaf(wB, vB.z, accB.z); accB.w = fmaf(wB, vB.w, accB.w);
    }
  }

  const float4 b4 = *reinterpret_cast<const float4*>(&bias[ql * 4]);
  {
    const float dv = fmaxf((float)degA, 1.0f);
    const float4 r4 = *reinterpret_cast<const float4*>(&R[(size_t)nodeA * 64 + ql * 4]);
    float4 o;
    o.x = fmaxf(accA.x / dv + b4.x + r4.x, 0.f);
    o.y = fmaxf(accA.y / dv + b4.y + r4.y, 0.f);
    o.z = fmaxf(accA.z / dv + b4.z + r4.z, 0.f);
    o.w = fmaxf(accA.w / dv + b4.w + r4.w, 0.f);
    *reinterpret_cast<float4*>(&h[(size_t)nodeA * 64 + ql * 4]) = o;
    if (keys != nullptr && ql == 15) keys[nodeA] = o.w;  // feature 63
  }
  if (okB) {
    const float dv = fmaxf((float)degB, 1.0f);
    const float4 r4 = *reinterpret_cast<const float4*>(&R[(size_t)nodeB * 64 + ql * 4]);
    float4 o;
    o.x = fmaxf(accB.x / dv + b4.x + r4.x, 0.f);
    o.y = fmaxf(accB.y / dv + b4.y + r4.y, 0.f);
    o.z = fmaxf(accB.z / dv + b4.z + r4.z, 0.f);
    o.w = fmaxf(accB.w / dv + b4.w + r4.w, 0.f);
    *reinterpret_cast<float4*>(&h[(size_t)nodeB * 64 + ql * 4]) = o;
    if (keys != nullptr && ql == 15) keys[nodeB] = o.w;
  }
}

// ---- fused layer: agg_n (gather into LDS h-tile) + proj_{n+1} (GEMM) ----
// Block b owns nodes [b*128, b*128+128). Gather = TWO nodes per quarter in
// flight (rows r, r+16): 32 P-gathers per chain vs 16 -> amortizes eidx
// latency. h tile in LDS [128][68]; GEMM reads W from global (L1 bcast).
__global__ __launch_bounds__(256) void layer_kernel(const float* __restrict__ P,
                                                    const float* __restrict__ R,
                                                    const float* __restrict__ bias,
                                                    const int* __restrict__ row_start,
                                                    const int* __restrict__ cnt,
                                                    const int* __restrict__ eidx,
                                                    const float* __restrict__ WL,
                                                    const float* __restrict__ WR,
                                                    float* __restrict__ Pout,
                                                    float* __restrict__ Rout) {
  __shared__ float hs[128 * 68];  // 34816 B
  const int t = threadIdx.x;
  const int lane = t & 63;
  const int qd = t >> 4;   // quarter id 0..15
  const int ql = t & 15;   // feature quarter
  const int row0 = blockIdx.x * 128;

  // ---- phase A: paired gather (mean aggr + bias + self + relu) into LDS ----
  for (int p = 0; p < 8; p += 2) {
    const int rA = qd + 16 * p;
    const int rB = rA + 16;
    const int nodeA = row0 + rA;
    const int nodeB = row0 + rB;
    const bool okA = (nodeA < NN), okB = (nodeB < NN);
    const int degA = okA ? cnt[nodeA] : 0;
    const int degB = okB ? cnt[nodeB] : 0;
    const int baseA = okA ? row_start[nodeA] : 0;
    const int baseB = okB ? row_start[nodeB] : 0;
    float4 accA = make_float4(0.f, 0.f, 0.f, 0.f);
    float4 accB = make_float4(0.f, 0.f, 0.f, 0.f);

    const int mx = max(degA, degB);
    for (int e0 = 0; e0 < mx; e0 += 16) {
      const int remA = degA - e0;
      const int remB = degB - e0;
      const int iiA = min(ql, max(remA - 1, 0));
      const int iiB = min(ql, max(remB - 1, 0));
      const int idxA = (remA > 0) ? eidx[baseA + e0 + iiA] : 0;
      const int idxB = (remB > 0) ? eidx[baseB + e0 + iiB] : 0;
#pragma unroll
      for (int j = 0; j < 16; ++j) {
        const int sA = __shfl(idxA, (lane & 48) | j);
        const int sB = __shfl(idxB, (lane & 48) | j);
        const float wA = (j < remA) ? 1.f : 0.f;
        const float wB = (j < remB) ? 1.f : 0.f;
        const float4 vA = *reinterpret_cast<const float4*>(&P[(size_t)sA * 64 + ql * 4]);
        const float4 vB = *reinterpret_cast<const float4*>(&P[(size_t)sB * 64 + ql * 4]);
        accA.x = fmaf(wA, vA.x, accA.x); accA.y = fmaf(wA, vA.y, accA.y);
        accA.z = fmaf(wA, vA.z, accA.z); accA.w = fmaf(wA, vA.w, accA.w);
        accB.x = fmaf(wB, vB.x, accB.x); accB.y = fmaf(wB, vB.y, accB.y);
        accB.z = fmaf(wB, vB.z, accB.z); accB.w = fmaf(wB, vB.w, accB.w);
      }
    }

    const float4 b4 = *reinterpret_cast<const float4*>(&bias[ql * 4]);
    if (okA) {
      const float dv = fmaxf((float)degA, 1.0f);
      const float4 r4 = *reinterpret_cast<const float4*>(&R[(size_t)nodeA * 64 + ql * 4]);
      accA.x = fmaxf(accA.x / dv + b4.x + r4.x, 0.f);
      accA.y = fmaxf(accA.y / dv + b4.y + r4.y, 0.f);
      accA.z = fmaxf(accA.z / dv + b4.z + r4.z, 0.f);
      accA.w = fmaxf(accA.w / dv + b4.w + r4.w, 0.f);
    } else {
      accA = make_float4(0.f, 0.f, 0.f, 0.f);
    }
    if (okB) {
      const float dv = fmaxf((float)degB, 1.0f);
      const float4 r4 = *reinterpret_cast<const float4*>(&R[(size_t)nodeB * 64 + ql * 4]);
      accB.x = fmaxf(accB.x / dv + b4.x + r4.x, 0.f);
      accB.y = fmaxf(accB.y / dv + b4.y + r4.y, 0.f);
      accB.z = fmaxf(accB.z / dv + b4.z + r4.z, 0.f);
      accB.w = fmaxf(accB.w / dv + b4.w + r4.w, 0.f);
    } else {
      accB = make_float4(0.f, 0.f, 0.f, 0.f);
    }
    *reinterpret_cast<float4*>(&hs[rA * 68 + ql * 4]) = accA;
    *reinterpret_cast<float4*>(&hs[rB * 68 + ql * 4]) = accB;
  }
  __syncthreads();

  // ---- phase B: [128x64] @ [64x128] GEMM, 8x8 reg tile per thread ----
  const int tc = t & 15, tr = t >> 4;
  const float* WB = (tc < 8) ? WL : WR;
  const int wcolg = (tc & 7) * 8;

  float acc[8][8];
#pragma unroll
  for (int i = 0; i < 8; ++i)
#pragma unroll
    for (int j = 0; j < 8; ++j) acc[i][j] = 0.f;

  for (int kk4 = 0; kk4 < 64; kk4 += 4) {
    float4 a[8];
#pragma unroll
    for (int i = 0; i < 8; ++i)
      a[i] = *reinterpret_cast<const float4*>(&hs[(tr + 16 * i) * 68 + kk4]);
#pragma unroll
    for (int kk = 0; kk < 4; ++kk) {
      float4 b0 = *reinterpret_cast<const float4*>(&WB[(kk4 + kk) * 64 + wcolg]);
      float4 b1 = *reinterpret_cast<const float4*>(&WB[(kk4 + kk) * 64 + wcolg + 4]);
      float bv[8] = {b0.x, b0.y, b0.z, b0.w, b1.x, b1.y, b1.z, b1.w};
#pragma unroll
      for (int i = 0; i < 8; ++i) {
        float av = (kk == 0) ? a[i].x : (kk == 1) ? a[i].y : (kk == 2) ? a[i].z : a[i].w;
#pragma unroll
        for (int j = 0; j < 8; ++j) acc[i][j] = fmaf(av, bv[j], acc[i][j]);
      }
    }
  }

  float* OUT = (tc < 8) ? Pout : Rout;
  const int cb = (tc & 7) * 8;
#pragma unroll
  for (int i = 0; i < 8; ++i) {
    int row = row0 + tr + 16 * i;
    if (row < NN) {
      *reinterpret_cast<float4*>(&OUT[(size_t)row * 64 + cb]) =
          make_float4(acc[i][0], acc[i][1], acc[i][2], acc[i][3]);
      *reinterpret_cast<float4*>(&OUT[(size_t)row * 64 + cb + 4]) =
          make_float4(acc[i][4], acc[i][5], acc[i][6], acc[i][7]);
    }
  }
}

// one block (256 thr) per graph: stable top-30, conv1d, MLP head.
__global__ __launch_bounds__(256) void head_kernel(const float* __restrict__ h,
                                                   const float* __restrict__ keysArr,
                                                   const float* __restrict__ cw,
                                                   const float* __restrict__ cb,
                                                   const float* __restrict__ w1,
                                                   const float* __restrict__ bb1,
                                                   const float* __restrict__ w2,
                                                   const float* __restrict__ bb2,
                                                   float* __restrict__ out) {
  __shared__ float key[PERG];
  __shared__ int sel[KK];
  __shared__ float feat[34 * 65];
  __shared__ float cwT[192 * 33];
  __shared__ float z[896];
  __shared__ float psum[256];
  const int g = blockIdx.x;
  const int t = threadIdx.x;

  for (int idx = t; idx < 32 * 192; idx += 256) {
    int o = idx / 192, k = idx % 192;
    cwT[k * 33 + o] = cw[idx];
  }
  if (t < PERG) key[t] = keysArr[g * PERG + t];
  __syncthreads();

  if (t < PERG) {
    float kv = key[t];
    int r = 0;
    for (int m = 0; m < PERG; ++m) {
      float km = key[m];
      r += (int)((km > kv) || (km == kv && m < t));
    }
    if (r < KK) sel[r] = t;
  }
  __syncthreads();

  for (int idx = t; idx < KK * HH; idx += 256) {
    int r = idx >> 6, f = idx & 63;
    feat[r * 65 + f] = h[(size_t)(g * PERG + sel[r]) * HH + f];
  }
  __syncthreads();

  {
    const int o = t & 31;
    const int pg = t >> 5;
    float zacc[4] = {0.f, 0.f, 0.f, 0.f};
    int i = 0, tt = 0;
    for (int k = 0; k < 192; ++k) {
      float c = cwT[k * 33 + o];
#pragma unroll
      for (int j = 0; j < 4; ++j) {
        int p = pg + 8 * j;
        zacc[j] = fmaf(c, feat[(p + tt) * 65 + i], zacc[j]);
      }
      if (++tt == 3) {
        tt = 0;
        ++i;
      }
    }
    float cbo = cb[o];
#pragma unroll
    for (int j = 0; j < 4; ++j) {
      int p = pg + 8 * j;
      if (p < 28) z[o * 28 + p] = fmaxf(zacc[j] + cbo, 0.f);
    }
  }
  __syncthreads();

  {
    const int hh = t & 63;
    const int quarter = t >> 6;
    const int q0 = quarter * 224;
    float acc = 0.f;
    for (int q = 0; q < 224; ++q)
      acc = fmaf(z[q0 + q], w1[(size_t)(q0 + q) * 64 + hh], acc);
    psum[t] = acc;
  }
  __syncthreads();

  if (t < 64) {
    float o1 = fmaxf(bb1[t] + psum[t] + psum[t + 64] + psum[t + 128] + psum[t + 192], 0.f);
    float v = o1 * w2[t];
#pragma unroll
    for (int off = 32; off > 0; off >>= 1) v += __shfl_down(v, off);
    if (t == 0) out[g] = v + bb2[0];
  }
}

extern "C" void kernel_launch(void* const* d_in, const int* in_sizes, int n_in,
                              void* d_out, int out_size, void* d_ws, size_t ws_size,
                              hipStream_t stream) {
  const float* x = (const float*)d_in[0];
  const int* src = (const int*)d_in[1];
  const int* dst = (const int*)d_in[2];
  const float* wl1 = (const float*)d_in[4];
  const float* wr1 = (const float*)d_in[5];
  const float* b1 = (const float*)d_in[6];
  const float* wl2 = (const float*)d_in[7];
  const float* wr2 = (const float*)d_in[8];
  const float* b2 = (const float*)d_in[9];
  const float* wl3 = (const float*)d_in[10];
  const float* wr3 = (const float*)d_in[11];
  const float* b3 = (const float*)d_in[12];
  const float* cw = (const float*)d_in[13];
  const float* cb = (const float*)d_in[14];
  const float* w1 = (const float*)d_in[15];
  const float* bb1 = (const float*)d_in[16];
  const float* w2 = (const float*)d_in[17];
  const float* bb2 = (const float*)d_in[18];
  float* out = (float*)d_out;

  char* w = (char*)d_ws;
  auto carve = [&](size_t bytes) {
    char* p = w;
    w += (bytes + 255) & ~(size_t)255;
    return p;
  };
  int* row_start = (int*)carve((size_t)NN * 4);
  int* cnt = (int*)carve((size_t)NN * 4);
  int* eidx = (int*)carve((size_t)EE * 4);
  float* P = (float*)carve((size_t)NN * 64 * 4);
  float* R = (float*)carve((size_t)NN * 64 * 4);
  float* hbuf = (float*)carve((size_t)NN * 64 * 4);
  float* R2 = (float*)carve((size_t)NN * 64 * 4);
  float* keys = (float*)carve((size_t)NN * 4);
  int* gcur = (int*)carve((size_t)NB * 4);
  // pairs aliases hbuf: csr reads pairs before layer1 writes P2=hbuf.
  int* pairs = (int*)hbuf;
  float* P2 = hbuf;

  hipMemsetAsync(gcur, 0, (size_t)NB * 4, stream);
  fused_bucket_proj<<<BUCKET_BLOCKS + PROJ_BLOCKS, 256, 0, stream>>>(
      src, dst, gcur, pairs, x, wl1, wr1, P, R);
  csr_kernel<<<NB, 256, 0, stream>>>(gcur, pairs, row_start, cnt, eidx);

  // layer1: agg(P,R,b1) -> LDS -> P2,R2 = h1 @ (wl2|wr2)
  layer_kernel<<<LAYER_BLOCKS, 256, 0, stream>>>(P, R, b1, row_start, cnt, eidx,
                                                 wl2, wr2, P2, R2);
  // layer2: agg(P2,R2,b2) -> LDS -> P,R = h2 @ (wl3|wr3)
  layer_kernel<<<LAYER_BLOCKS, 256, 0, stream>>>(P2, R2, b2, row_start, cnt, eidx,
                                                 wl3, wr3, P, R);
  // layer3 (final): agg(P,R,b3) -> h (hbuf) + keys
  const int aggGrid = (NN + 31) / 32;  // 8 nodes per wave (paired), 4 waves/block
  agg_kernel<<<aggGrid, 256, 0, stream>>>(P, R, b3, row_start, cnt, eidx, hbuf, keys);
  head_kernel<<<GG, 256, 0, stream>>>(hbuf, keys, cw, cb, w1, bb1, w2, bb2, out);
}

// Round 6
// 487.442 us; speedup vs baseline: 4.6739x; 1.0477x over previous
//
#include <hip/hip_runtime.h>

#define NN 100000
#define EE 1600000
#define GG 1000
#define PERG 100
#define KK 30
#define HH 64

#define NB 782      // buckets of 128 nodes: 782*128 = 100096 >= NN
#define CAP 4096    // max edges/bucket (mean 2048, sigma ~45 -> huge margin)
#define CHB 4096    // edges per bucket block -> 391 bucket blocks
#define BUCKET_BLOCKS ((EE + CHB - 1) / CHB)  // 391
#define PROJ_BLOCKS ((NN + 127) / 128)        // 782
#define LAYER_BLOCKS ((NN + 63) / 64)         // 1563 (BM=64 tiles)

// ---- bucket body: LDS histogram + per-(block,bucket) run reservation ----
__device__ __forceinline__ void bucket_body(int bid, float* smem,
                                            const int* __restrict__ src,
                                            const int* __restrict__ dst,
                                            int* __restrict__ gcur,
                                            int* __restrict__ pairs) {
  int* lhist = (int*)smem;
  int* lbase = lhist + NB;
  int* lcur = lbase + NB;
  const int t = threadIdx.x;
  const int c0 = bid * CHB;
  const int c1 = min(c0 + CHB, EE);
  for (int b = t; b < NB; b += 256) {
    lhist[b] = 0;
    lcur[b] = 0;
  }
  __syncthreads();
  for (int e = c0 + t; e < c1; e += 256) atomicAdd(&lhist[dst[e] >> 7], 1);
  __syncthreads();
  for (int b = t; b < NB; b += 256) {
    int c = lhist[b];
    lbase[b] = c ? atomicAdd(&gcur[b], c) : 0;
  }
  __syncthreads();
  for (int e = c0 + t; e < c1; e += 256) {
    int d = dst[e];
    int b = d >> 7;
    int p = atomicAdd(&lcur[b], 1);
    pairs[b * CAP + lbase[b] + p] = (src[e] << 7) | (d & 127);
  }
}

// ---- proj body: X [NN,K] @ (WL|WR) -> P, R. BM=128, 8x8 reg tile ----
template <int K>
__device__ __forceinline__ void proj_body(int bid, float* smem,
                                          const float* __restrict__ X,
                                          const float* __restrict__ WL,
                                          const float* __restrict__ WR,
                                          float* __restrict__ P,
                                          float* __restrict__ R) {
  constexpr int BM = 128, BK = 32, XSP = 40, WSP = 144;
  float* xs = smem;             // 128*40 floats
  float* ws = smem + BM * XSP;  // 32*144 floats
  const int t = threadIdx.x;
  const int row0 = bid * BM;
  const int tc = t & 15, tr = t >> 4;
  const int wcol = tc * 8 + (tc >> 2) * 4;

  float acc[8][8];
#pragma unroll
  for (int i = 0; i < 8; ++i)
#pragma unroll
    for (int j = 0; j < 8; ++j) acc[i][j] = 0.f;

  for (int k0 = 0; k0 < K; k0 += BK) {
    __syncthreads();
    for (int idx = t; idx < BM * 8; idx += 256) {
      int r = idx >> 3, c = idx & 7;
      int row = row0 + r;
      float4 v = make_float4(0.f, 0.f, 0.f, 0.f);
      if (row < NN) v = *reinterpret_cast<const float4*>(&X[(size_t)row * K + k0 + c * 4]);
      *reinterpret_cast<float4*>(&xs[r * XSP + c * 4]) = v;
    }
    for (int idx = t; idx < BK * 16; idx += 256) {
      int kr = idx >> 4, c4 = idx & 15;
      int gcl = c4 >> 1;
      int off = gcl * 8 + (gcl >> 2) * 4 + (c4 & 1) * 4;
      *reinterpret_cast<float4*>(&ws[kr * WSP + off]) =
          *reinterpret_cast<const float4*>(&WL[(k0 + kr) * 64 + c4 * 4]);
      int g2 = gcl + 8;
      int off2 = g2 * 8 + (g2 >> 2) * 4 + (c4 & 1) * 4;
      *reinterpret_cast<float4*>(&ws[kr * WSP + off2]) =
          *reinterpret_cast<const float4*>(&WR[(k0 + kr) * 64 + c4 * 4]);
    }
    __syncthreads();
    for (int kk4 = 0; kk4 < BK; kk4 += 4) {
      float4 a[8];
#pragma unroll
      for (int i = 0; i < 8; ++i)
        a[i] = *reinterpret_cast<const float4*>(&xs[(tr + 16 * i) * XSP + kk4]);
#pragma unroll
      for (int kk = 0; kk < 4; ++kk) {
        float4 b0 = *reinterpret_cast<const float4*>(&ws[(kk4 + kk) * WSP + wcol]);
        float4 b1 = *reinterpret_cast<const float4*>(&ws[(kk4 + kk) * WSP + wcol + 4]);
        float bv[8] = {b0.x, b0.y, b0.z, b0.w, b1.x, b1.y, b1.z, b1.w};
#pragma unroll
        for (int i = 0; i < 8; ++i) {
          float av = (kk == 0) ? a[i].x : (kk == 1) ? a[i].y : (kk == 2) ? a[i].z : a[i].w;
#pragma unroll
          for (int j = 0; j < 8; ++j) acc[i][j] = fmaf(av, bv[j], acc[i][j]);
        }
      }
    }
  }

  float* OUT = (tc < 8) ? P : R;
  int cb = (tc & 7) * 8;
#pragma unroll
  for (int i = 0; i < 8; ++i) {
    int row = row0 + tr + 16 * i;
    if (row < NN) {
      *reinterpret_cast<float4*>(&OUT[(size_t)row * 64 + cb]) =
          make_float4(acc[i][0], acc[i][1], acc[i][2], acc[i][3]);
      *reinterpret_cast<float4*>(&OUT[(size_t)row * 64 + cb + 4]) =
          make_float4(acc[i][4], acc[i][5], acc[i][6], acc[i][7]);
    }
  }
}

// Heterogeneous launch: proj blocks first (all resident), buckets backfill.
__global__ __launch_bounds__(256) void fused_bucket_proj(const int* __restrict__ src,
                                                         const int* __restrict__ dst,
                                                         int* __restrict__ gcur,
                                                         int* __restrict__ pairs,
                                                         const float* __restrict__ X,
                                                         const float* __restrict__ WL,
                                                         const float* __restrict__ WR,
                                                         float* __restrict__ P,
                                                         float* __restrict__ R) {
  __shared__ float smem[128 * 40 + 32 * 144];  // 38912 B, covers both roles
  if (blockIdx.x < PROJ_BLOCKS)
    proj_body<128>(blockIdx.x, smem, X, WL, WR, P, R);
  else
    bucket_body(blockIdx.x - PROJ_BLOCKS, smem, src, dst, gcur, pairs);
}

// Phase C with inline scan: block b computes base = sum(gcur[0..b)) itself
// (<=782 L2-cached ints), then 128-bin LDS counting sort -> row_start/cnt/eidx.
__global__ __launch_bounds__(256) void csr_kernel(const int* __restrict__ gcur,
                                                  const int* __restrict__ pairs,
                                                  int* __restrict__ row_start,
                                                  int* __restrict__ cnt,
                                                  int* __restrict__ eidx) {
  __shared__ int vals[CAP];
  __shared__ int hist[128];
  __shared__ int offs[128];
  __shared__ int cur[128];
  __shared__ int red[4];
  const int b = blockIdx.x;
  const int t = threadIdx.x;
  int s = 0;
  for (int i = t; i < b; i += 256) s += gcur[i];
#pragma unroll
  for (int off = 32; off > 0; off >>= 1) s += __shfl_xor(s, off);
  if ((t & 63) == 0) red[t >> 6] = s;
  if (t < 128) {
    hist[t] = 0;
    cur[t] = 0;
  }
  __syncthreads();
  const int base = red[0] + red[1] + red[2] + red[3];
  const int nb = gcur[b];
  for (int i = t; i < nb; i += 256) {
    int v = pairs[b * CAP + i];
    vals[i] = v;
    atomicAdd(&hist[v & 127], 1);
  }
  __syncthreads();
  if (t < 128) {
    int ss = 0;
    for (int m = 0; m < t; ++m) ss += hist[m];
    offs[t] = ss;
    int node = b * 128 + t;
    if (node < NN) {
      row_start[node] = base + ss;
      cnt[node] = hist[t];
    }
  }
  __syncthreads();
  for (int i = t; i < nb; i += 256) {
    int v = vals[i];
    int ld = v & 127;
    int p = atomicAdd(&cur[ld], 1);
    eidx[base + offs[ld] + p] = v >> 7;
  }
}

// agg v2 (verified round 2): quarter per node, lane = feature quarter.
__global__ __launch_bounds__(256) void agg_kernel(const float* __restrict__ P,
                                                  const float* __restrict__ R,
                                                  const float* __restrict__ bias,
                                                  const int* __restrict__ row_start,
                                                  const int* __restrict__ cnt,
                                                  const int* __restrict__ eidx,
                                                  float* __restrict__ h,
                                                  float* __restrict__ keys) {
  const int wv = (blockIdx.x * 256 + threadIdx.x) >> 6;  // wave id
  const int lane = threadIdx.x & 63;
  const int q = lane >> 4;   // node slot within wave
  const int ql = lane & 15;  // feature quarter
  const int node = wv * 4 + q;
  if (node >= NN) return;
  const int base = row_start[node];
  const int deg = cnt[node];
  float4 acc = make_float4(0.f, 0.f, 0.f, 0.f);

  for (int e0 = 0; e0 < deg; e0 += 16) {
    const int rem = deg - e0;
    const int ii = (ql < rem) ? ql : (rem - 1);
    int idx = eidx[base + e0 + ii];
#pragma unroll
    for (int j = 0; j < 16; ++j) {
      const int sj = __shfl(idx, (lane & 48) | j);
      const float wj = (j < rem) ? 1.f : 0.f;
      const float4 vj = *reinterpret_cast<const float4*>(&P[(size_t)sj * 64 + ql * 4]);
      acc.x = fmaf(wj, vj.x, acc.x);
      acc.y = fmaf(wj, vj.y, acc.y);
      acc.z = fmaf(wj, vj.z, acc.z);
      acc.w = fmaf(wj, vj.w, acc.w);
    }
  }

  const float dv = fmaxf((float)deg, 1.0f);
  float4 r4 = *reinterpret_cast<const float4*>(&R[(size_t)node * 64 + ql * 4]);
  float4 b4 = *reinterpret_cast<const float4*>(&bias[ql * 4]);
  float4 o;
  o.x = fmaxf(acc.x / dv + b4.x + r4.x, 0.f);
  o.y = fmaxf(acc.y / dv + b4.y + r4.y, 0.f);
  o.z = fmaxf(acc.z / dv + b4.z + r4.z, 0.f);
  o.w = fmaxf(acc.w / dv + b4.w + r4.w, 0.f);
  *reinterpret_cast<float4*>(&h[(size_t)node * 64 + ql * 4]) = o;
  if (keys != nullptr && ql == 15) keys[node] = o.w;  // feature 63
}

// ---- fused layer, BM=64: agg_n (gather into LDS) + proj_{n+1} (GEMM) ----
// LDS 64*68*4 = 17408 B -> 8 blocks/CU (wave-slot cap) vs BM=128's 4.
// 2x resident waves for the latency-bound gather phase. Gather = verified
// v2 single-node-per-quarter (16 loads in flight). GEMM: 4x8 acc/thread.
__global__ __launch_bounds__(256) void layer_kernel(const float* __restrict__ P,
                                                    const float* __restrict__ R,
                                                    const float* __restrict__ bias,
                                                    const int* __restrict__ row_start,
                                                    const int* __restrict__ cnt,
                                                    const int* __restrict__ eidx,
                                                    const float* __restrict__ WL,
                                                    const float* __restrict__ WR,
                                                    float* __restrict__ Pout,
                                                    float* __restrict__ Rout) {
  __shared__ float hs[64 * 68];  // 17408 B
  const int t = threadIdx.x;
  const int lane = t & 63;
  const int qd = t >> 4;   // quarter id 0..15
  const int ql = t & 15;   // feature quarter
  const int row0 = blockIdx.x * 64;

  // ---- phase A: gather (mean aggr + bias + self + relu) into LDS ----
  for (int p = 0; p < 4; ++p) {
    const int r = qd + 16 * p;
    const int node = row0 + r;
    float4 acc = make_float4(0.f, 0.f, 0.f, 0.f);
    if (node < NN) {
      const int base = row_start[node];
      const int deg = cnt[node];
      for (int e0 = 0; e0 < deg; e0 += 16) {
        const int rem = deg - e0;
        const int ii = (ql < rem) ? ql : (rem - 1);
        int idx = eidx[base + e0 + ii];
#pragma unroll
        for (int j = 0; j < 16; ++j) {
          const int sj = __shfl(idx, (lane & 48) | j);
          const float wj = (j < rem) ? 1.f : 0.f;
          const float4 vj = *reinterpret_cast<const float4*>(&P[(size_t)sj * 64 + ql * 4]);
          acc.x = fmaf(wj, vj.x, acc.x);
          acc.y = fmaf(wj, vj.y, acc.y);
          acc.z = fmaf(wj, vj.z, acc.z);
          acc.w = fmaf(wj, vj.w, acc.w);
        }
      }
      const float dv = fmaxf((float)deg, 1.0f);
      const float4 r4 = *reinterpret_cast<const float4*>(&R[(size_t)node * 64 + ql * 4]);
      const float4 b4 = *reinterpret_cast<const float4*>(&bias[ql * 4]);
      acc.x = fmaxf(acc.x / dv + b4.x + r4.x, 0.f);
      acc.y = fmaxf(acc.y / dv + b4.y + r4.y, 0.f);
      acc.z = fmaxf(acc.z / dv + b4.z + r4.z, 0.f);
      acc.w = fmaxf(acc.w / dv + b4.w + r4.w, 0.f);
    }
    *reinterpret_cast<float4*>(&hs[r * 68 + ql * 4]) = acc;
  }
  __syncthreads();

  // ---- phase B: [64x64] @ [64x128] GEMM, 4x8 reg tile per thread ----
  const int tc = t & 15, tr = t >> 4;
  const float* WB = (tc < 8) ? WL : WR;
  const int wcolg = (tc & 7) * 8;

  float acc[4][8];
#pragma unroll
  for (int i = 0; i < 4; ++i)
#pragma unroll
    for (int j = 0; j < 8; ++j) acc[i][j] = 0.f;

  for (int kk4 = 0; kk4 < 64; kk4 += 4) {
    float4 a[4];
#pragma unroll
    for (int i = 0; i < 4; ++i)
      a[i] = *reinterpret_cast<const float4*>(&hs[(tr + 16 * i) * 68 + kk4]);
#pragma unroll
    for (int kk = 0; kk < 4; ++kk) {
      float4 b0 = *reinterpret_cast<const float4*>(&WB[(kk4 + kk) * 64 + wcolg]);
      float4 b1 = *reinterpret_cast<const float4*>(&WB[(kk4 + kk) * 64 + wcolg + 4]);
      float bv[8] = {b0.x, b0.y, b0.z, b0.w, b1.x, b1.y, b1.z, b1.w};
#pragma unroll
      for (int i = 0; i < 4; ++i) {
        float av = (kk == 0) ? a[i].x : (kk == 1) ? a[i].y : (kk == 2) ? a[i].z : a[i].w;
#pragma unroll
        for (int j = 0; j < 8; ++j) acc[i][j] = fmaf(av, bv[j], acc[i][j]);
      }
    }
  }

  float* OUT = (tc < 8) ? Pout : Rout;
  const int cb = (tc & 7) * 8;
#pragma unroll
  for (int i = 0; i < 4; ++i) {
    int row = row0 + tr + 16 * i;
    if (row < NN) {
      *reinterpret_cast<float4*>(&OUT[(size_t)row * 64 + cb]) =
          make_float4(acc[i][0], acc[i][1], acc[i][2], acc[i][3]);
      *reinterpret_cast<float4*>(&OUT[(size_t)row * 64 + cb + 4]) =
          make_float4(acc[i][4], acc[i][5], acc[i][6], acc[i][7]);
    }
  }
}

// one block (256 thr) per graph: stable top-30, conv1d, MLP head.
__global__ __launch_bounds__(256) void head_kernel(const float* __restrict__ h,
                                                   const float* __restrict__ keysArr,
                                                   const float* __restrict__ cw,
                                                   const float* __restrict__ cb,
                                                   const float* __restrict__ w1,
                                                   const float* __restrict__ bb1,
                                                   const float* __restrict__ w2,
                                                   const float* __restrict__ bb2,
                                                   float* __restrict__ out) {
  __shared__ float key[PERG];
  __shared__ int sel[KK];
  __shared__ float feat[34 * 65];
  __shared__ float cwT[192 * 33];
  __shared__ float z[896];
  __shared__ float psum[256];
  const int g = blockIdx.x;
  const int t = threadIdx.x;

  for (int idx = t; idx < 32 * 192; idx += 256) {
    int o = idx / 192, k = idx % 192;
    cwT[k * 33 + o] = cw[idx];
  }
  if (t < PERG) key[t] = keysArr[g * PERG + t];
  __syncthreads();

  if (t < PERG) {
    float kv = key[t];
    int r = 0;
    for (int m = 0; m < PERG; ++m) {
      float km = key[m];
      r += (int)((km > kv) || (km == kv && m < t));
    }
    if (r < KK) sel[r] = t;
  }
  __syncthreads();

  for (int idx = t; idx < KK * HH; idx += 256) {
    int r = idx >> 6, f = idx & 63;
    feat[r * 65 + f] = h[(size_t)(g * PERG + sel[r]) * HH + f];
  }
  __syncthreads();

  {
    const int o = t & 31;
    const int pg = t >> 5;
    float zacc[4] = {0.f, 0.f, 0.f, 0.f};
    int i = 0, tt = 0;
    for (int k = 0; k < 192; ++k) {
      float c = cwT[k * 33 + o];
#pragma unroll
      for (int j = 0; j < 4; ++j) {
        int p = pg + 8 * j;
        zacc[j] = fmaf(c, feat[(p + tt) * 65 + i], zacc[j]);
      }
      if (++tt == 3) {
        tt = 0;
        ++i;
      }
    }
    float cbo = cb[o];
#pragma unroll
    for (int j = 0; j < 4; ++j) {
      int p = pg + 8 * j;
      if (p < 28) z[o * 28 + p] = fmaxf(zacc[j] + cbo, 0.f);
    }
  }
  __syncthreads();

  {
    const int hh = t & 63;
    const int quarter = t >> 6;
    const int q0 = quarter * 224;
    float acc = 0.f;
    for (int q = 0; q < 224; ++q)
      acc = fmaf(z[q0 + q], w1[(size_t)(q0 + q) * 64 + hh], acc);
    psum[t] = acc;
  }
  __syncthreads();

  if (t < 64) {
    float o1 = fmaxf(bb1[t] + psum[t] + psum[t + 64] + psum[t + 128] + psum[t + 192], 0.f);
    float v = o1 * w2[t];
#pragma unroll
    for (int off = 32; off > 0; off >>= 1) v += __shfl_down(v, off);
    if (t == 0) out[g] = v + bb2[0];
  }
}

extern "C" void kernel_launch(void* const* d_in, const int* in_sizes, int n_in,
                              void* d_out, int out_size, void* d_ws, size_t ws_size,
                              hipStream_t stream) {
  const float* x = (const float*)d_in[0];
  const int* src = (const int*)d_in[1];
  const int* dst = (const int*)d_in[2];
  const float* wl1 = (const float*)d_in[4];
  const float* wr1 = (const float*)d_in[5];
  const float* b1 = (const float*)d_in[6];
  const float* wl2 = (const float*)d_in[7];
  const float* wr2 = (const float*)d_in[8];
  const float* b2 = (const float*)d_in[9];
  const float* wl3 = (const float*)d_in[10];
  const float* wr3 = (const float*)d_in[11];
  const float* b3 = (const float*)d_in[12];
  const float* cw = (const float*)d_in[13];
  const float* cb = (const float*)d_in[14];
  const float* w1 = (const float*)d_in[15];
  const float* bb1 = (const float*)d_in[16];
  const float* w2 = (const float*)d_in[17];
  const float* bb2 = (const float*)d_in[18];
  float* out = (float*)d_out;

  char* w = (char*)d_ws;
  auto carve = [&](size_t bytes) {
    char* p = w;
    w += (bytes + 255) & ~(size_t)255;
    return p;
  };
  int* row_start = (int*)carve((size_t)NN * 4);
  int* cnt = (int*)carve((size_t)NN * 4);
  int* eidx = (int*)carve((size_t)EE * 4);
  float* P = (float*)carve((size_t)NN * 64 * 4);
  float* R = (float*)carve((size_t)NN * 64 * 4);
  float* hbuf = (float*)carve((size_t)NN * 64 * 4);
  float* R2 = (float*)carve((size_t)NN * 64 * 4);
  float* keys = (float*)carve((size_t)NN * 4);
  int* gcur = (int*)carve((size_t)NB * 4);
  // pairs aliases hbuf: csr reads pairs before layer1 writes P2=hbuf.
  int* pairs = (int*)hbuf;
  float* P2 = hbuf;

  hipMemsetAsync(gcur, 0, (size_t)NB * 4, stream);
  fused_bucket_proj<<<BUCKET_BLOCKS + PROJ_BLOCKS, 256, 0, stream>>>(
      src, dst, gcur, pairs, x, wl1, wr1, P, R);
  csr_kernel<<<NB, 256, 0, stream>>>(gcur, pairs, row_start, cnt, eidx);

  // layer1: agg(P,R,b1) -> LDS -> P2,R2 = h1 @ (wl2|wr2)
  layer_kernel<<<LAYER_BLOCKS, 256, 0, stream>>>(P, R, b1, row_start, cnt, eidx,
                                                 wl2, wr2, P2, R2);
  // layer2: agg(P2,R2,b2) -> LDS -> P,R = h2 @ (wl3|wr3)
  layer_kernel<<<LAYER_BLOCKS, 256, 0, stream>>>(P2, R2, b2, row_start, cnt, eidx,
                                                 wl3, wr3, P, R);
  // layer3 (final): agg(P,R,b3) -> h (hbuf) + keys
  const int aggGrid = (NN + 15) / 16;  // 4 nodes per wave, 4 waves per block
  agg_kernel<<<aggGrid, 256, 0, stream>>>(P, R, b3, row_start, cnt, eidx, hbuf, keys);
  head_kernel<<<GG, 256, 0, stream>>>(hbuf, keys, cw, cb, w1, bb1, w2, bb2, out);
}

// Round 7
// 452.765 us; speedup vs baseline: 5.0319x; 1.0766x over previous
//
#include <hip/hip_runtime.h>

#define NN 100000
#define EE 1600000
#define GG 1000
#define PERG 100
#define KK 30
#define HH 64

#define NB 782      // buckets of 128 nodes: 782*128 = 100096 >= NN
#define CAP 4096    // max edges/bucket (mean 2048, sigma ~45 -> huge margin)
#define CHB 4096    // edges per bucket block -> 391 bucket blocks
#define BUCKET_BLOCKS ((EE + CHB - 1) / CHB)  // 391
#define PROJ_BLOCKS ((NN + 127) / 128)        // 782
#define LAYER_BLOCKS ((NN + 63) / 64)         // 1563 (BM=64 tiles)

// ---- bucket body: LDS histogram + per-(block,bucket) run reservation ----
__device__ __forceinline__ void bucket_body(int bid, float* smem,
                                            const int* __restrict__ src,
                                            const int* __restrict__ dst,
                                            int* __restrict__ gcur,
                                            int* __restrict__ pairs) {
  int* lhist = (int*)smem;
  int* lbase = lhist + NB;
  int* lcur = lbase + NB;
  const int t = threadIdx.x;
  const int c0 = bid * CHB;
  const int c1 = min(c0 + CHB, EE);
  for (int b = t; b < NB; b += 256) {
    lhist[b] = 0;
    lcur[b] = 0;
  }
  __syncthreads();
  for (int e = c0 + t; e < c1; e += 256) atomicAdd(&lhist[dst[e] >> 7], 1);
  __syncthreads();
  for (int b = t; b < NB; b += 256) {
    int c = lhist[b];
    lbase[b] = c ? atomicAdd(&gcur[b], c) : 0;
  }
  __syncthreads();
  for (int e = c0 + t; e < c1; e += 256) {
    int d = dst[e];
    int b = d >> 7;
    int p = atomicAdd(&lcur[b], 1);
    pairs[b * CAP + lbase[b] + p] = (src[e] << 7) | (d & 127);
  }
}

// ---- proj body: X [NN,K] @ (WL|WR) -> P, R. BM=128, 8x8 reg tile ----
// XSP=36 (was 40): xs-read bank pattern (36*tr)%32 = 4*tr%32 -> 2-way (free)
// vs 40's 4-way conflict.
template <int K>
__device__ __forceinline__ void proj_body(int bid, float* smem,
                                          const float* __restrict__ X,
                                          const float* __restrict__ WL,
                                          const float* __restrict__ WR,
                                          float* __restrict__ P,
                                          float* __restrict__ R) {
  constexpr int BM = 128, BK = 32, XSP = 36, WSP = 144;
  float* xs = smem;             // 128*36 floats
  float* ws = smem + BM * XSP;  // 32*144 floats
  const int t = threadIdx.x;
  const int row0 = bid * BM;
  const int tc = t & 15, tr = t >> 4;
  const int wcol = tc * 8 + (tc >> 2) * 4;

  float acc[8][8];
#pragma unroll
  for (int i = 0; i < 8; ++i)
#pragma unroll
    for (int j = 0; j < 8; ++j) acc[i][j] = 0.f;

  for (int k0 = 0; k0 < K; k0 += BK) {
    __syncthreads();
    for (int idx = t; idx < BM * 8; idx += 256) {
      int r = idx >> 3, c = idx & 7;
      int row = row0 + r;
      float4 v = make_float4(0.f, 0.f, 0.f, 0.f);
      if (row < NN) v = *reinterpret_cast<const float4*>(&X[(size_t)row * K + k0 + c * 4]);
      *reinterpret_cast<float4*>(&xs[r * XSP + c * 4]) = v;
    }
    for (int idx = t; idx < BK * 16; idx += 256) {
      int kr = idx >> 4, c4 = idx & 15;
      int gcl = c4 >> 1;
      int off = gcl * 8 + (gcl >> 2) * 4 + (c4 & 1) * 4;
      *reinterpret_cast<float4*>(&ws[kr * WSP + off]) =
          *reinterpret_cast<const float4*>(&WL[(k0 + kr) * 64 + c4 * 4]);
      int g2 = gcl + 8;
      int off2 = g2 * 8 + (g2 >> 2) * 4 + (c4 & 1) * 4;
      *reinterpret_cast<float4*>(&ws[kr * WSP + off2]) =
          *reinterpret_cast<const float4*>(&WR[(k0 + kr) * 64 + c4 * 4]);
    }
    __syncthreads();
    for (int kk4 = 0; kk4 < BK; kk4 += 4) {
      float4 a[8];
#pragma unroll
      for (int i = 0; i < 8; ++i)
        a[i] = *reinterpret_cast<const float4*>(&xs[(tr + 16 * i) * XSP + kk4]);
#pragma unroll
      for (int kk = 0; kk < 4; ++kk) {
        float4 b0 = *reinterpret_cast<const float4*>(&ws[(kk4 + kk) * WSP + wcol]);
        float4 b1 = *reinterpret_cast<const float4*>(&ws[(kk4 + kk) * WSP + wcol + 4]);
        float bv[8] = {b0.x, b0.y, b0.z, b0.w, b1.x, b1.y, b1.z, b1.w};
#pragma unroll
        for (int i = 0; i < 8; ++i) {
          float av = (kk == 0) ? a[i].x : (kk == 1) ? a[i].y : (kk == 2) ? a[i].z : a[i].w;
#pragma unroll
          for (int j = 0; j < 8; ++j) acc[i][j] = fmaf(av, bv[j], acc[i][j]);
        }
      }
    }
  }

  float* OUT = (tc < 8) ? P : R;
  int cb = (tc & 7) * 8;
#pragma unroll
  for (int i = 0; i < 8; ++i) {
    int row = row0 + tr + 16 * i;
    if (row < NN) {
      *reinterpret_cast<float4*>(&OUT[(size_t)row * 64 + cb]) =
          make_float4(acc[i][0], acc[i][1], acc[i][2], acc[i][3]);
      *reinterpret_cast<float4*>(&OUT[(size_t)row * 64 + cb + 4]) =
          make_float4(acc[i][4], acc[i][5], acc[i][6], acc[i][7]);
    }
  }
}

// Heterogeneous launch: proj blocks first (all resident), buckets backfill.
__global__ __launch_bounds__(256) void fused_bucket_proj(const int* __restrict__ src,
                                                         const int* __restrict__ dst,
                                                         int* __restrict__ gcur,
                                                         int* __restrict__ pairs,
                                                         const float* __restrict__ X,
                                                         const float* __restrict__ WL,
                                                         const float* __restrict__ WR,
                                                         float* __restrict__ P,
                                                         float* __restrict__ R) {
  __shared__ float smem[128 * 36 + 32 * 144];  // 36864 B, covers both roles
  if (blockIdx.x < PROJ_BLOCKS)
    proj_body<128>(blockIdx.x, smem, X, WL, WR, P, R);
  else
    bucket_body(blockIdx.x - PROJ_BLOCKS, smem, src, dst, gcur, pairs);
}

// Phase C with inline scan: block b computes base = sum(gcur[0..b)) itself
// (<=782 L2-cached ints), then 128-bin LDS counting sort -> row_start/cnt/eidx.
__global__ __launch_bounds__(256) void csr_kernel(const int* __restrict__ gcur,
                                                  const int* __restrict__ pairs,
                                                  int* __restrict__ row_start,
                                                  int* __restrict__ cnt,
                                                  int* __restrict__ eidx) {
  __shared__ int vals[CAP];
  __shared__ int hist[128];
  __shared__ int offs[128];
  __shared__ int cur[128];
  __shared__ int red[4];
  const int b = blockIdx.x;
  const int t = threadIdx.x;
  int s = 0;
  for (int i = t; i < b; i += 256) s += gcur[i];
#pragma unroll
  for (int off = 32; off > 0; off >>= 1) s += __shfl_xor(s, off);
  if ((t & 63) == 0) red[t >> 6] = s;
  if (t < 128) {
    hist[t] = 0;
    cur[t] = 0;
  }
  __syncthreads();
  const int base = red[0] + red[1] + red[2] + red[3];
  const int nb = gcur[b];
  for (int i = t; i < nb; i += 256) {
    int v = pairs[b * CAP + i];
    vals[i] = v;
    atomicAdd(&hist[v & 127], 1);
  }
  __syncthreads();
  if (t < 128) {
    int ss = 0;
    for (int m = 0; m < t; ++m) ss += hist[m];
    offs[t] = ss;
    int node = b * 128 + t;
    if (node < NN) {
      row_start[node] = base + ss;
      cnt[node] = hist[t];
    }
  }
  __syncthreads();
  for (int i = t; i < nb; i += 256) {
    int v = vals[i];
    int ld = v & 127;
    int p = atomicAdd(&cur[ld], 1);
    eidx[base + offs[ld] + p] = v >> 7;
  }
}

// ---- fused layer, BM=64: agg_n (gather into LDS) + proj_{n+1} (GEMM) ----
// keyP/keyR (nullable): epilogue also writes packed column 63 of Pout/Rout
// (the layer-3 sort-key sources) -> 400KB tables, L2-resident for keys_kernel.
__global__ __launch_bounds__(256) void layer_kernel(const float* __restrict__ P,
                                                    const float* __restrict__ R,
                                                    const float* __restrict__ bias,
                                                    const int* __restrict__ row_start,
                                                    const int* __restrict__ cnt,
                                                    const int* __restrict__ eidx,
                                                    const float* __restrict__ WL,
                                                    const float* __restrict__ WR,
                                                    float* __restrict__ Pout,
                                                    float* __restrict__ Rout,
                                                    float* __restrict__ keyP,
                                                    float* __restrict__ keyR) {
  __shared__ float hs[64 * 68];  // 17408 B
  const int t = threadIdx.x;
  const int lane = t & 63;
  const int qd = t >> 4;   // quarter id 0..15
  const int ql = t & 15;   // feature quarter
  const int row0 = blockIdx.x * 64;

  // ---- phase A: gather (mean aggr + bias + self + relu) into LDS ----
  for (int p = 0; p < 4; ++p) {
    const int r = qd + 16 * p;
    const int node = row0 + r;
    float4 acc = make_float4(0.f, 0.f, 0.f, 0.f);
    if (node < NN) {
      const int base = row_start[node];
      const int deg = cnt[node];
      for (int e0 = 0; e0 < deg; e0 += 16) {
        const int rem = deg - e0;
        const int ii = (ql < rem) ? ql : (rem - 1);
        int idx = eidx[base + e0 + ii];
#pragma unroll
        for (int j = 0; j < 16; ++j) {
          const int sj = __shfl(idx, (lane & 48) | j);
          const float wj = (j < rem) ? 1.f : 0.f;
          const float4 vj = *reinterpret_cast<const float4*>(&P[(size_t)sj * 64 + ql * 4]);
          acc.x = fmaf(wj, vj.x, acc.x);
          acc.y = fmaf(wj, vj.y, acc.y);
          acc.z = fmaf(wj, vj.z, acc.z);
          acc.w = fmaf(wj, vj.w, acc.w);
        }
      }
      const float dv = fmaxf((float)deg, 1.0f);
      const float4 r4 = *reinterpret_cast<const float4*>(&R[(size_t)node * 64 + ql * 4]);
      const float4 b4 = *reinterpret_cast<const float4*>(&bias[ql * 4]);
      acc.x = fmaxf(acc.x / dv + b4.x + r4.x, 0.f);
      acc.y = fmaxf(acc.y / dv + b4.y + r4.y, 0.f);
      acc.z = fmaxf(acc.z / dv + b4.z + r4.z, 0.f);
      acc.w = fmaxf(acc.w / dv + b4.w + r4.w, 0.f);
    }
    *reinterpret_cast<float4*>(&hs[r * 68 + ql * 4]) = acc;
  }
  __syncthreads();

  // ---- phase B: [64x64] @ [64x128] GEMM, 4x8 reg tile per thread ----
  const int tc = t & 15, tr = t >> 4;
  const float* WB = (tc < 8) ? WL : WR;
  const int wcolg = (tc & 7) * 8;

  float acc[4][8];
#pragma unroll
  for (int i = 0; i < 4; ++i)
#pragma unroll
    for (int j = 0; j < 8; ++j) acc[i][j] = 0.f;

  for (int kk4 = 0; kk4 < 64; kk4 += 4) {
    float4 a[4];
#pragma unroll
    for (int i = 0; i < 4; ++i)
      a[i] = *reinterpret_cast<const float4*>(&hs[(tr + 16 * i) * 68 + kk4]);
#pragma unroll
    for (int kk = 0; kk < 4; ++kk) {
      float4 b0 = *reinterpret_cast<const float4*>(&WB[(kk4 + kk) * 64 + wcolg]);
      float4 b1 = *reinterpret_cast<const float4*>(&WB[(kk4 + kk) * 64 + wcolg + 4]);
      float bv[8] = {b0.x, b0.y, b0.z, b0.w, b1.x, b1.y, b1.z, b1.w};
#pragma unroll
      for (int i = 0; i < 4; ++i) {
        float av = (kk == 0) ? a[i].x : (kk == 1) ? a[i].y : (kk == 2) ? a[i].z : a[i].w;
#pragma unroll
        for (int j = 0; j < 8; ++j) acc[i][j] = fmaf(av, bv[j], acc[i][j]);
      }
    }
  }

  float* OUT = (tc < 8) ? Pout : Rout;
  const int cb = (tc & 7) * 8;
#pragma unroll
  for (int i = 0; i < 4; ++i) {
    int row = row0 + tr + 16 * i;
    if (row < NN) {
      *reinterpret_cast<float4*>(&OUT[(size_t)row * 64 + cb]) =
          make_float4(acc[i][0], acc[i][1], acc[i][2], acc[i][3]);
      *reinterpret_cast<float4*>(&OUT[(size_t)row * 64 + cb + 4]) =
          make_float4(acc[i][4], acc[i][5], acc[i][6], acc[i][7]);
      if (keyP != nullptr && tc == 7) keyP[row] = acc[i][7];    // Pout col 63
      if (keyR != nullptr && tc == 15) keyR[row] = acc[i][7];   // Rout col 63
    }
  }
}

// keys pass: lane per node; mean over keyP[neighbors] (400KB L2-resident
// table) + b3[63] + keyR -> relu -> keys[node]. 16-deep independent loads.
__global__ __launch_bounds__(256) void keys_kernel(const float* __restrict__ keyP,
                                                   const float* __restrict__ keyR,
                                                   const float* __restrict__ b3,
                                                   const int* __restrict__ row_start,
                                                   const int* __restrict__ cnt,
                                                   const int* __restrict__ eidx,
                                                   float* __restrict__ keys) {
  const int node = blockIdx.x * 256 + threadIdx.x;
  if (node >= NN) return;
  const int base = row_start[node];
  const int deg = cnt[node];
  float s = 0.f;
  for (int e0 = 0; e0 < deg; e0 += 16) {
    const int rem = deg - e0;
    int id[16];
#pragma unroll
    for (int k = 0; k < 16; ++k) id[k] = eidx[base + e0 + ((k < rem) ? k : rem - 1)];
    float v[16];
#pragma unroll
    for (int k = 0; k < 16; ++k) v[k] = keyP[id[k]];
#pragma unroll
    for (int k = 0; k < 16; ++k) s += (k < rem) ? v[k] : 0.f;
  }
  const float dv = fmaxf((float)deg, 1.f);
  keys[node] = fmaxf(s / dv + b3[63] + keyR[node], 0.f);
}

// selection + compact gather: block g picks its top-30 (stable rank, exact
// same comparator as before), then gathers full h3 rows ONLY for those 30
// nodes -> feat[G][30][64]. 30% of the agg3 gather volume; h3 never
// materialized for unselected nodes.
__global__ __launch_bounds__(256) void sel_gather(const float* __restrict__ P,
                                                  const float* __restrict__ R,
                                                  const float* __restrict__ bias,
                                                  const float* __restrict__ keysArr,
                                                  const int* __restrict__ row_start,
                                                  const int* __restrict__ cnt,
                                                  const int* __restrict__ eidx,
                                                  float* __restrict__ feat) {
  __shared__ float key[PERG];
  __shared__ int sel[32];
  const int g = blockIdx.x;
  const int t = threadIdx.x;
  if (t < PERG) key[t] = keysArr[g * PERG + t];
  __syncthreads();
  if (t < PERG) {
    float kv = key[t];
    int r = 0;
    for (int m = 0; m < PERG; ++m) {
      float km = key[m];
      r += (int)((km > kv) || (km == kv && m < t));
    }
    if (r < KK) sel[r] = t;
  }
  __syncthreads();

  const int lane = t & 63;
  const int qd = t >> 4;   // quarter id 0..15
  const int ql = t & 15;   // feature quarter
  for (int p = 0; p < 2; ++p) {
    const int r = qd + 16 * p;
    if (r < KK) {  // quarter-uniform branch; shfl stays within the quarter
      const int node = g * PERG + sel[r];
      const int base = row_start[node];
      const int deg = cnt[node];
      float4 acc = make_float4(0.f, 0.f, 0.f, 0.f);
      for (int e0 = 0; e0 < deg; e0 += 16) {
        const int rem = deg - e0;
        const int ii = (ql < rem) ? ql : (rem - 1);
        int idx = eidx[base + e0 + ii];
#pragma unroll
        for (int j = 0; j < 16; ++j) {
          const int sj = __shfl(idx, (lane & 48) | j);
          const float wj = (j < rem) ? 1.f : 0.f;
          const float4 vj = *reinterpret_cast<const float4*>(&P[(size_t)sj * 64 + ql * 4]);
          acc.x = fmaf(wj, vj.x, acc.x);
          acc.y = fmaf(wj, vj.y, acc.y);
          acc.z = fmaf(wj, vj.z, acc.z);
          acc.w = fmaf(wj, vj.w, acc.w);
        }
      }
      const float dv = fmaxf((float)deg, 1.0f);
      const float4 r4 = *reinterpret_cast<const float4*>(&R[(size_t)node * 64 + ql * 4]);
      const float4 b4 = *reinterpret_cast<const float4*>(&bias[ql * 4]);
      float4 o;
      o.x = fmaxf(acc.x / dv + b4.x + r4.x, 0.f);
      o.y = fmaxf(acc.y / dv + b4.y + r4.y, 0.f);
      o.z = fmaxf(acc.z / dv + b4.z + r4.z, 0.f);
      o.w = fmaxf(acc.w / dv + b4.w + r4.w, 0.f);
      *reinterpret_cast<float4*>(&feat[((size_t)g * KK + r) * 64 + ql * 4]) = o;
    }
  }
}

// one block (256 thr) per graph: conv1d + MLP head over compact feat.
__global__ __launch_bounds__(256) void head_kernel(const float* __restrict__ gfeat,
                                                   const float* __restrict__ cw,
                                                   const float* __restrict__ cb,
                                                   const float* __restrict__ w1,
                                                   const float* __restrict__ bb1,
                                                   const float* __restrict__ w2,
                                                   const float* __restrict__ bb2,
                                                   float* __restrict__ out) {
  __shared__ float feat[34 * 65];
  __shared__ float cwT[192 * 33];
  __shared__ float z[896];
  __shared__ float psum[256];
  const int g = blockIdx.x;
  const int t = threadIdx.x;

  for (int idx = t; idx < 32 * 192; idx += 256) {
    int o = idx / 192, k = idx % 192;
    cwT[k * 33 + o] = cw[idx];
  }
  for (int idx = t; idx < KK * HH; idx += 256) {
    int r = idx >> 6, f = idx & 63;
    feat[r * 65 + f] = gfeat[((size_t)g * KK + r) * 64 + f];
  }
  __syncthreads();

  {
    const int o = t & 31;
    const int pg = t >> 5;
    float zacc[4] = {0.f, 0.f, 0.f, 0.f};
    int i = 0, tt = 0;
    for (int k = 0; k < 192; ++k) {
      float c = cwT[k * 33 + o];
#pragma unroll
      for (int j = 0; j < 4; ++j) {
        int p = pg + 8 * j;
        zacc[j] = fmaf(c, feat[(p + tt) * 65 + i], zacc[j]);
      }
      if (++tt == 3) {
        tt = 0;
        ++i;
      }
    }
    float cbo = cb[o];
#pragma unroll
    for (int j = 0; j < 4; ++j) {
      int p = pg + 8 * j;
      if (p < 28) z[o * 28 + p] = fmaxf(zacc[j] + cbo, 0.f);
    }
  }
  __syncthreads();

  {
    const int hh = t & 63;
    const int quarter = t >> 6;
    const int q0 = quarter * 224;
    float acc = 0.f;
    for (int q = 0; q < 224; ++q)
      acc = fmaf(z[q0 + q], w1[(size_t)(q0 + q) * 64 + hh], acc);
    psum[t] = acc;
  }
  __syncthreads();

  if (t < 64) {
    float o1 = fmaxf(bb1[t] + psum[t] + psum[t + 64] + psum[t + 128] + psum[t + 192], 0.f);
    float v = o1 * w2[t];
#pragma unroll
    for (int off = 32; off > 0; off >>= 1) v += __shfl_down(v, off);
    if (t == 0) out[g] = v + bb2[0];
  }
}

extern "C" void kernel_launch(void* const* d_in, const int* in_sizes, int n_in,
                              void* d_out, int out_size, void* d_ws, size_t ws_size,
                              hipStream_t stream) {
  const float* x = (const float*)d_in[0];
  const int* src = (const int*)d_in[1];
  const int* dst = (const int*)d_in[2];
  const float* wl1 = (const float*)d_in[4];
  const float* wr1 = (const float*)d_in[5];
  const float* b1 = (const float*)d_in[6];
  const float* wl2 = (const float*)d_in[7];
  const float* wr2 = (const float*)d_in[8];
  const float* b2 = (const float*)d_in[9];
  const float* wl3 = (const float*)d_in[10];
  const float* wr3 = (const float*)d_in[11];
  const float* b3 = (const float*)d_in[12];
  const float* cw = (const float*)d_in[13];
  const float* cb = (const float*)d_in[14];
  const float* w1 = (const float*)d_in[15];
  const float* bb1 = (const float*)d_in[16];
  const float* w2 = (const float*)d_in[17];
  const float* bb2 = (const float*)d_in[18];
  float* out = (float*)d_out;

  char* w = (char*)d_ws;
  auto carve = [&](size_t bytes) {
    char* p = w;
    w += (bytes + 255) & ~(size_t)255;
    return p;
  };
  int* row_start = (int*)carve((size_t)NN * 4);
  int* cnt = (int*)carve((size_t)NN * 4);
  int* eidx = (int*)carve((size_t)EE * 4);
  float* P = (float*)carve((size_t)NN * 64 * 4);
  float* R = (float*)carve((size_t)NN * 64 * 4);
  float* P2 = (float*)carve((size_t)NN * 64 * 4);
  float* R2 = (float*)carve((size_t)NN * 64 * 4);
  float* keys = (float*)carve((size_t)NN * 4);
  float* keyP = (float*)carve((size_t)NN * 4);
  float* keyR = (float*)carve((size_t)NN * 4);
  float* feat = (float*)carve((size_t)GG * KK * HH * 4);  // 7.68 MB
  int* gcur = (int*)carve((size_t)NB * 4);
  // pairs aliases P2: csr consumes pairs before layer1 writes P2.
  int* pairs = (int*)P2;  // NB*CAP*4 = 12.8 MB < 25.6 MB

  hipMemsetAsync(gcur, 0, (size_t)NB * 4, stream);
  fused_bucket_proj<<<BUCKET_BLOCKS + PROJ_BLOCKS, 256, 0, stream>>>(
      src, dst, gcur, pairs, x, wl1, wr1, P, R);
  csr_kernel<<<NB, 256, 0, stream>>>(gcur, pairs, row_start, cnt, eidx);

  // layer1: agg(P,R,b1) -> LDS -> P2,R2 = h1 @ (wl2|wr2)
  layer_kernel<<<LAYER_BLOCKS, 256, 0, stream>>>(P, R, b1, row_start, cnt, eidx,
                                                 wl2, wr2, P2, R2, nullptr, nullptr);
  // layer2: agg(P2,R2,b2) -> LDS -> P,R = h2 @ (wl3|wr3); also packs col-63
  layer_kernel<<<LAYER_BLOCKS, 256, 0, stream>>>(P2, R2, b2, row_start, cnt, eidx,
                                                 wl3, wr3, P, R, keyP, keyR);
  // layer3 keys only (L2-resident 400KB tables)
  keys_kernel<<<(NN + 255) / 256, 256, 0, stream>>>(keyP, keyR, b3, row_start, cnt,
                                                    eidx, keys);
  // selection + compact full-row gather for the 30k selected nodes
  sel_gather<<<GG, 256, 0, stream>>>(P, R, b3, keys, row_start, cnt, eidx, feat);
  head_kernel<<<GG, 256, 0, stream>>>(feat, cw, cb, w1, bb1, w2, bb2, out);
}

// Round 9
// 436.909 us; speedup vs baseline: 5.2145x; 1.0363x over previous
//
#include <hip/hip_runtime.h>

#define NN 100000
#define EE 1600000
#define GG 1000
#define PERG 100
#define KK 30
#define HH 64

#define NB 782      // buckets of 128 nodes: 782*128 = 100096 >= NN
#define CAP 4096    // max edges/bucket (mean 2048, sigma ~45 -> huge margin)
#define CHB 4096    // edges per bucket block -> 391 bucket blocks
#define BUCKET_BLOCKS ((EE + CHB - 1) / CHB)  // 391
#define PROJ_BLOCKS ((NN + 127) / 128)        // 782
#define LAYER_BLOCKS ((NN + 63) / 64)         // 1563 (BM=64 tiles)

typedef _Float16 half4_t __attribute__((ext_vector_type(4)));
typedef _Float16 half8_t __attribute__((ext_vector_type(8)));

// ---- bucket body: LDS histogram + per-(block,bucket) run reservation ----
__device__ __forceinline__ void bucket_body(int bid, float* smem,
                                            const int* __restrict__ src,
                                            const int* __restrict__ dst,
                                            int* __restrict__ gcur,
                                            int* __restrict__ pairs) {
  int* lhist = (int*)smem;
  int* lbase = lhist + NB;
  int* lcur = lbase + NB;
  const int t = threadIdx.x;
  const int c0 = bid * CHB;
  const int c1 = min(c0 + CHB, EE);
  for (int b = t; b < NB; b += 256) {
    lhist[b] = 0;
    lcur[b] = 0;
  }
  __syncthreads();
  for (int e = c0 + t; e < c1; e += 256) atomicAdd(&lhist[dst[e] >> 7], 1);
  __syncthreads();
  for (int b = t; b < NB; b += 256) {
    int c = lhist[b];
    lbase[b] = c ? atomicAdd(&gcur[b], c) : 0;
  }
  __syncthreads();
  for (int e = c0 + t; e < c1; e += 256) {
    int d = dst[e];
    int b = d >> 7;
    int p = atomicAdd(&lcur[b], 1);
    pairs[b * CAP + lbase[b] + p] = (src[e] << 7) | (d & 127);
  }
}

// ---- proj body: X [NN,K] @ (WL|WR) -> P, R (both fp32). BM=128 ----
template <int K>
__device__ __forceinline__ void proj_body(int bid, float* smem,
                                          const float* __restrict__ X,
                                          const float* __restrict__ WL,
                                          const float* __restrict__ WR,
                                          float* __restrict__ P,
                                          float* __restrict__ R) {
  constexpr int BM = 128, BK = 32, XSP = 36, WSP = 144;
  float* xs = smem;             // 128*36 floats
  float* ws = smem + BM * XSP;  // 32*144 floats
  const int t = threadIdx.x;
  const int row0 = bid * BM;
  const int tc = t & 15, tr = t >> 4;
  const int wcol = tc * 8 + (tc >> 2) * 4;

  float acc[8][8];
#pragma unroll
  for (int i = 0; i < 8; ++i)
#pragma unroll
    for (int j = 0; j < 8; ++j) acc[i][j] = 0.f;

  for (int k0 = 0; k0 < K; k0 += BK) {
    __syncthreads();
    for (int idx = t; idx < BM * 8; idx += 256) {
      int r = idx >> 3, c = idx & 7;
      int row = row0 + r;
      float4 v = make_float4(0.f, 0.f, 0.f, 0.f);
      if (row < NN) v = *reinterpret_cast<const float4*>(&X[(size_t)row * K + k0 + c * 4]);
      *reinterpret_cast<float4*>(&xs[r * XSP + c * 4]) = v;
    }
    for (int idx = t; idx < BK * 16; idx += 256) {
      int kr = idx >> 4, c4 = idx & 15;
      int gcl = c4 >> 1;
      int off = gcl * 8 + (gcl >> 2) * 4 + (c4 & 1) * 4;
      *reinterpret_cast<float4*>(&ws[kr * WSP + off]) =
          *reinterpret_cast<const float4*>(&WL[(k0 + kr) * 64 + c4 * 4]);
      int g2 = gcl + 8;
      int off2 = g2 * 8 + (g2 >> 2) * 4 + (c4 & 1) * 4;
      *reinterpret_cast<float4*>(&ws[kr * WSP + off2]) =
          *reinterpret_cast<const float4*>(&WR[(k0 + kr) * 64 + c4 * 4]);
    }
    __syncthreads();
    for (int kk4 = 0; kk4 < BK; kk4 += 4) {
      float4 a[8];
#pragma unroll
      for (int i = 0; i < 8; ++i)
        a[i] = *reinterpret_cast<const float4*>(&xs[(tr + 16 * i) * XSP + kk4]);
#pragma unroll
      for (int kk = 0; kk < 4; ++kk) {
        float4 b0 = *reinterpret_cast<const float4*>(&ws[(kk4 + kk) * WSP + wcol]);
        float4 b1 = *reinterpret_cast<const float4*>(&ws[(kk4 + kk) * WSP + wcol + 4]);
        float bv[8] = {b0.x, b0.y, b0.z, b0.w, b1.x, b1.y, b1.z, b1.w};
#pragma unroll
        for (int i = 0; i < 8; ++i) {
          float av = (kk == 0) ? a[i].x : (kk == 1) ? a[i].y : (kk == 2) ? a[i].z : a[i].w;
#pragma unroll
          for (int j = 0; j < 8; ++j) acc[i][j] = fmaf(av, bv[j], acc[i][j]);
        }
      }
    }
  }

  float* OUT = (tc < 8) ? P : R;
  int cb = (tc & 7) * 8;
#pragma unroll
  for (int i = 0; i < 8; ++i) {
    int row = row0 + tr + 16 * i;
    if (row < NN) {
      *reinterpret_cast<float4*>(&OUT[(size_t)row * 64 + cb]) =
          make_float4(acc[i][0], acc[i][1], acc[i][2], acc[i][3]);
      *reinterpret_cast<float4*>(&OUT[(size_t)row * 64 + cb + 4]) =
          make_float4(acc[i][4], acc[i][5], acc[i][6], acc[i][7]);
    }
  }
}

// Heterogeneous launch: proj blocks first (all resident), buckets backfill.
__global__ __launch_bounds__(256) void fused_bucket_proj(const int* __restrict__ src,
                                                         const int* __restrict__ dst,
                                                         int* __restrict__ gcur,
                                                         int* __restrict__ pairs,
                                                         const float* __restrict__ X,
                                                         const float* __restrict__ WL,
                                                         const float* __restrict__ WR,
                                                         float* __restrict__ P,
                                                         float* __restrict__ R) {
  __shared__ float smem[128 * 36 + 32 * 144];  // 36864 B, covers both roles
  if (blockIdx.x < PROJ_BLOCKS)
    proj_body<128>(blockIdx.x, smem, X, WL, WR, P, R);
  else
    bucket_body(blockIdx.x - PROJ_BLOCKS, smem, src, dst, gcur, pairs);
}

// Phase C with inline scan -> row_start/cnt/eidx (CSR sorted by dst).
__global__ __launch_bounds__(256) void csr_kernel(const int* __restrict__ gcur,
                                                  const int* __restrict__ pairs,
                                                  int* __restrict__ row_start,
                                                  int* __restrict__ cnt,
                                                  int* __restrict__ eidx) {
  __shared__ int vals[CAP];
  __shared__ int hist[128];
  __shared__ int offs[128];
  __shared__ int cur[128];
  __shared__ int red[4];
  const int b = blockIdx.x;
  const int t = threadIdx.x;
  int s = 0;
  for (int i = t; i < b; i += 256) s += gcur[i];
#pragma unroll
  for (int off = 32; off > 0; off >>= 1) s += __shfl_xor(s, off);
  if ((t & 63) == 0) red[t >> 6] = s;
  if (t < 128) {
    hist[t] = 0;
    cur[t] = 0;
  }
  __syncthreads();
  const int base = red[0] + red[1] + red[2] + red[3];
  const int nb = gcur[b];
  for (int i = t; i < nb; i += 256) {
    int v = pairs[b * CAP + i];
    vals[i] = v;
    atomicAdd(&hist[v & 127], 1);
  }
  __syncthreads();
  if (t < 128) {
    int ss = 0;
    for (int m = 0; m < t; ++m) ss += hist[m];
    offs[t] = ss;
    int node = b * 128 + t;
    if (node < NN) {
      row_start[node] = base + ss;
      cnt[node] = hist[t];
    }
  }
  __syncthreads();
  for (int i = t; i < nb; i += 256) {
    int v = vals[i];
    int ld = v & 127;
    int p = atomicAdd(&cur[ld], 1);
    eidx[base + offs[ld] + p] = v >> 7;
  }
}

// ---- fused layer, BM=64: agg_n (fp32 gather into LDS) + proj_{n+1} GEMM ----
// HOUT=false: Pout fp32 (next layer's gather table must stay fp32 — the
// RANKING path; fp16 here flipped top-30 selections, absmax 0.137 in r8).
// HOUT=true (layer2): P output written as fp16 PoutH — consumed ONLY by
// sel_head's post-selection feature gather (error ~5e-4, keys untouched);
// also packs fp32 col-63 keyP/keyR (the exact ranking inputs).
template <bool HOUT>
__global__ __launch_bounds__(256) void layer_kernel(const float* __restrict__ P,
                                                    const float* __restrict__ R,
                                                    const float* __restrict__ bias,
                                                    const int* __restrict__ row_start,
                                                    const int* __restrict__ cnt,
                                                    const int* __restrict__ eidx,
                                                    const float* __restrict__ WL,
                                                    const float* __restrict__ WR,
                                                    float* __restrict__ Pout,
                                                    _Float16* __restrict__ PoutH,
                                                    float* __restrict__ Rout,
                                                    float* __restrict__ keyP,
                                                    float* __restrict__ keyR) {
  __shared__ float hs[64 * 68];  // 17408 B
  const int t = threadIdx.x;
  const int lane = t & 63;
  const int qd = t >> 4;   // quarter id 0..15
  const int ql = t & 15;   // feature quarter
  const int row0 = blockIdx.x * 64;

  // ---- phase A: gather (mean aggr + bias + self + relu) into LDS ----
  for (int p = 0; p < 4; ++p) {
    const int r = qd + 16 * p;
    const int node = row0 + r;
    float4 acc = make_float4(0.f, 0.f, 0.f, 0.f);
    if (node < NN) {
      const int base = row_start[node];
      const int deg = cnt[node];
      for (int e0 = 0; e0 < deg; e0 += 16) {
        const int rem = deg - e0;
        const int ii = (ql < rem) ? ql : (rem - 1);
        int idx = eidx[base + e0 + ii];
#pragma unroll
        for (int j = 0; j < 16; ++j) {
          const int sj = __shfl(idx, (lane & 48) | j);
          const float wj = (j < rem) ? 1.f : 0.f;
          const float4 vj = *reinterpret_cast<const float4*>(&P[(size_t)sj * 64 + ql * 4]);
          acc.x = fmaf(wj, vj.x, acc.x);
          acc.y = fmaf(wj, vj.y, acc.y);
          acc.z = fmaf(wj, vj.z, acc.z);
          acc.w = fmaf(wj, vj.w, acc.w);
        }
      }
      const float dv = fmaxf((float)deg, 1.0f);
      const float4 r4 = *reinterpret_cast<const float4*>(&R[(size_t)node * 64 + ql * 4]);
      const float4 b4 = *reinterpret_cast<const float4*>(&bias[ql * 4]);
      acc.x = fmaxf(acc.x / dv + b4.x + r4.x, 0.f);
      acc.y = fmaxf(acc.y / dv + b4.y + r4.y, 0.f);
      acc.z = fmaxf(acc.z / dv + b4.z + r4.z, 0.f);
      acc.w = fmaxf(acc.w / dv + b4.w + r4.w, 0.f);
    }
    *reinterpret_cast<float4*>(&hs[r * 68 + ql * 4]) = acc;
  }
  __syncthreads();

  // ---- phase B: [64x64] @ [64x128] GEMM, 4x8 reg tile per thread ----
  const int tc = t & 15, tr = t >> 4;
  const float* WB = (tc < 8) ? WL : WR;
  const int wcolg = (tc & 7) * 8;

  float acc[4][8];
#pragma unroll
  for (int i = 0; i < 4; ++i)
#pragma unroll
    for (int j = 0; j < 8; ++j) acc[i][j] = 0.f;

  for (int kk4 = 0; kk4 < 64; kk4 += 4) {
    float4 a[4];
#pragma unroll
    for (int i = 0; i < 4; ++i)
      a[i] = *reinterpret_cast<const float4*>(&hs[(tr + 16 * i) * 68 + kk4]);
#pragma unroll
    for (int kk = 0; kk < 4; ++kk) {
      float4 b0 = *reinterpret_cast<const float4*>(&WB[(kk4 + kk) * 64 + wcolg]);
      float4 b1 = *reinterpret_cast<const float4*>(&WB[(kk4 + kk) * 64 + wcolg + 4]);
      float bv[8] = {b0.x, b0.y, b0.z, b0.w, b1.x, b1.y, b1.z, b1.w};
#pragma unroll
      for (int i = 0; i < 4; ++i) {
        float av = (kk == 0) ? a[i].x : (kk == 1) ? a[i].y : (kk == 2) ? a[i].z : a[i].w;
#pragma unroll
        for (int j = 0; j < 8; ++j) acc[i][j] = fmaf(av, bv[j], acc[i][j]);
      }
    }
  }

  const int cb = (tc & 7) * 8;
  if (tc < 8) {
#pragma unroll
    for (int i = 0; i < 4; ++i) {
      int row = row0 + tr + 16 * i;
      if (row < NN) {
        if (HOUT) {
          half8_t hv;
#pragma unroll
          for (int j = 0; j < 8; ++j) hv[j] = (_Float16)acc[i][j];
          *reinterpret_cast<half8_t*>(&PoutH[(size_t)row * 64 + cb]) = hv;
          if (keyP != nullptr && tc == 7) keyP[row] = acc[i][7];  // col63 fp32
        } else {
          *reinterpret_cast<float4*>(&Pout[(size_t)row * 64 + cb]) =
              make_float4(acc[i][0], acc[i][1], acc[i][2], acc[i][3]);
          *reinterpret_cast<float4*>(&Pout[(size_t)row * 64 + cb + 4]) =
              make_float4(acc[i][4], acc[i][5], acc[i][6], acc[i][7]);
        }
      }
    }
  } else {
#pragma unroll
    for (int i = 0; i < 4; ++i) {
      int row = row0 + tr + 16 * i;
      if (row < NN) {
        *reinterpret_cast<float4*>(&Rout[(size_t)row * 64 + cb]) =
            make_float4(acc[i][0], acc[i][1], acc[i][2], acc[i][3]);
        *reinterpret_cast<float4*>(&Rout[(size_t)row * 64 + cb + 4]) =
            make_float4(acc[i][4], acc[i][5], acc[i][6], acc[i][7]);
        if (HOUT && keyR != nullptr && tc == 15) keyR[row] = acc[i][7];
      }
    }
  }
}

// ---- sel_head: per-graph keys (fp32, exact) + top-30 selection + compact
// layer-3 gather (fp16 table, post-selection -> bounded error) + conv1d + MLP.
__global__ __launch_bounds__(256) void sel_head(const _Float16* __restrict__ Ph,
                                                const float* __restrict__ R,
                                                const float* __restrict__ b3,
                                                const float* __restrict__ keyP,
                                                const float* __restrict__ keyR,
                                                const int* __restrict__ row_start,
                                                const int* __restrict__ cnt,
                                                const int* __restrict__ eidx,
                                                const float* __restrict__ cw,
                                                const float* __restrict__ cb,
                                                const float* __restrict__ w1,
                                                const float* __restrict__ bb1,
                                                const float* __restrict__ w2,
                                                const float* __restrict__ bb2,
                                                float* __restrict__ out) {
  __shared__ float key[PERG];
  __shared__ int sel[32];
  __shared__ float feat[34 * 65];
  __shared__ float cwT[192 * 33];
  __shared__ float z[896];
  __shared__ float psum[256];
  const int g = blockIdx.x;
  const int t = threadIdx.x;

  // conv-weight transpose staging runs concurrently with key computation
  for (int idx = t; idx < 32 * 192; idx += 256) {
    int o = idx / 192, k = idx % 192;
    cwT[k * 33 + o] = cw[idx];
  }
  if (t < PERG) {
    const int node = g * PERG + t;
    const int base = row_start[node];
    const int deg = cnt[node];
    float s = 0.f;
    for (int e = 0; e < deg; ++e) s += keyP[eidx[base + e]];
    key[t] = fmaxf(s / fmaxf((float)deg, 1.f) + b3[63] + keyR[node], 0.f);
  }
  __syncthreads();

  if (t < PERG) {
    float kv = key[t];
    int r = 0;
    for (int m = 0; m < PERG; ++m) {
      float km = key[m];
      r += (int)((km > kv) || (km == kv && m < t));
    }
    if (r < KK) sel[r] = t;
  }
  __syncthreads();

  // compact gather: 30 selected nodes, full 64-feature layer-3 aggregation
  const int lane = t & 63;
  const int qd = t >> 4;   // quarter id 0..15
  const int ql = t & 15;   // feature quarter
  for (int p = 0; p < 2; ++p) {
    const int r = qd + 16 * p;
    if (r < KK) {  // quarter-uniform branch; shfl stays within the quarter
      const int node = g * PERG + sel[r];
      const int base = row_start[node];
      const int deg = cnt[node];
      float4 acc = make_float4(0.f, 0.f, 0.f, 0.f);
      for (int e0 = 0; e0 < deg; e0 += 16) {
        const int rem = deg - e0;
        const int ii = (ql < rem) ? ql : (rem - 1);
        int idx = eidx[base + e0 + ii];
#pragma unroll
        for (int j = 0; j < 16; ++j) {
          const int sj = __shfl(idx, (lane & 48) | j);
          const float wj = (j < rem) ? 1.f : 0.f;
          const half4_t hv =
              *reinterpret_cast<const half4_t*>(&Ph[(size_t)sj * 64 + ql * 4]);
          acc.x = fmaf(wj, (float)hv.x, acc.x);
          acc.y = fmaf(wj, (float)hv.y, acc.y);
          acc.z = fmaf(wj, (float)hv.z, acc.z);
          acc.w = fmaf(wj, (float)hv.w, acc.w);
        }
      }
      const float dv = fmaxf((float)deg, 1.0f);
      const float4 r4 = *reinterpret_cast<const float4*>(&R[(size_t)node * 64 + ql * 4]);
      const float4 b4 = *reinterpret_cast<const float4*>(&b3[ql * 4]);
      feat[r * 65 + ql * 4 + 0] = fmaxf(acc.x / dv + b4.x + r4.x, 0.f);
      feat[r * 65 + ql * 4 + 1] = fmaxf(acc.y / dv + b4.y + r4.y, 0.f);
      feat[r * 65 + ql * 4 + 2] = fmaxf(acc.z / dv + b4.z + r4.z, 0.f);
      feat[r * 65 + ql * 4 + 3] = fmaxf(acc.w / dv + b4.w + r4.w, 0.f);
    }
  }
  __syncthreads();

  {
    const int o = t & 31;
    const int pg = t >> 5;
    float zacc[4] = {0.f, 0.f, 0.f, 0.f};
    int i = 0, tt = 0;
    for (int k = 0; k < 192; ++k) {
      float c = cwT[k * 33 + o];
#pragma unroll
      for (int j = 0; j < 4; ++j) {
        int p = pg + 8 * j;
        zacc[j] = fmaf(c, feat[(p + tt) * 65 + i], zacc[j]);
      }
      if (++tt == 3) {
        tt = 0;
        ++i;
      }
    }
    float cbo = cb[o];
#pragma unroll
    for (int j = 0; j < 4; ++j) {
      int p = pg + 8 * j;
      if (p < 28) z[o * 28 + p] = fmaxf(zacc[j] + cbo, 0.f);
    }
  }
  __syncthreads();

  {
    const int hh = t & 63;
    const int quarter = t >> 6;
    const int q0 = quarter * 224;
    float acc = 0.f;
    for (int q = 0; q < 224; ++q)
      acc = fmaf(z[q0 + q], w1[(size_t)(q0 + q) * 64 + hh], acc);
    psum[t] = acc;
  }
  __syncthreads();

  if (t < 64) {
    float o1 = fmaxf(bb1[t] + psum[t] + psum[t + 64] + psum[t + 128] + psum[t + 192], 0.f);
    float v = o1 * w2[t];
#pragma unroll
    for (int off = 32; off > 0; off >>= 1) v += __shfl_down(v, off);
    if (t == 0) out[g] = v + bb2[0];
  }
}

extern "C" void kernel_launch(void* const* d_in, const int* in_sizes, int n_in,
                              void* d_out, int out_size, void* d_ws, size_t ws_size,
                              hipStream_t stream) {
  const float* x = (const float*)d_in[0];
  const int* src = (const int*)d_in[1];
  const int* dst = (const int*)d_in[2];
  const float* wl1 = (const float*)d_in[4];
  const float* wr1 = (const float*)d_in[5];
  const float* b1 = (const float*)d_in[6];
  const float* wl2 = (const float*)d_in[7];
  const float* wr2 = (const float*)d_in[8];
  const float* b2 = (const float*)d_in[9];
  const float* wl3 = (const float*)d_in[10];
  const float* wr3 = (const float*)d_in[11];
  const float* b3 = (const float*)d_in[12];
  const float* cw = (const float*)d_in[13];
  const float* cb = (const float*)d_in[14];
  const float* w1 = (const float*)d_in[15];
  const float* bb1 = (const float*)d_in[16];
  const float* w2 = (const float*)d_in[17];
  const float* bb2 = (const float*)d_in[18];
  float* out = (float*)d_out;

  char* w = (char*)d_ws;
  auto carve = [&](size_t bytes) {
    char* p = w;
    w += (bytes + 255) & ~(size_t)255;
    return p;
  };
  int* row_start = (int*)carve((size_t)NN * 4);
  int* cnt = (int*)carve((size_t)NN * 4);
  int* eidx = (int*)carve((size_t)EE * 4);
  float* P1 = (float*)carve((size_t)NN * 64 * 4);
  float* R1 = (float*)carve((size_t)NN * 64 * 4);
  float* P2 = (float*)carve((size_t)NN * 64 * 4);
  float* R2 = (float*)carve((size_t)NN * 64 * 4);
  _Float16* PhF = (_Float16*)carve((size_t)NN * 64 * 2);  // final gather table
  float* keyP = (float*)carve((size_t)NN * 4);
  float* keyR = (float*)carve((size_t)NN * 4);
  int* gcur = (int*)carve((size_t)NB * 4);
  // pairs aliases P2: csr consumes pairs before layer1 writes P2.
  int* pairs = (int*)P2;

  hipMemsetAsync(gcur, 0, (size_t)NB * 4, stream);
  fused_bucket_proj<<<BUCKET_BLOCKS + PROJ_BLOCKS, 256, 0, stream>>>(
      src, dst, gcur, pairs, x, wl1, wr1, P1, R1);
  csr_kernel<<<NB, 256, 0, stream>>>(gcur, pairs, row_start, cnt, eidx);

  // layer1 (fp32 out): agg(P1,R1,b1) -> P2,R2 = h1 @ (wl2|wr2)
  layer_kernel<false><<<LAYER_BLOCKS, 256, 0, stream>>>(
      P1, R1, b1, row_start, cnt, eidx, wl2, wr2, P2, nullptr, R2, nullptr, nullptr);
  // layer2 (fp16 P out + fp32 keys): agg(P2,R2,b2) -> PhF,R1 = h2 @ (wl3|wr3)
  layer_kernel<true><<<LAYER_BLOCKS, 256, 0, stream>>>(
      P2, R2, b2, row_start, cnt, eidx, wl3, wr3, nullptr, PhF, R1, keyP, keyR);
  // keys (fp32 exact) + selection + compact fp16 gather + conv + MLP
  sel_head<<<GG, 256, 0, stream>>>(PhF, R1, b3, keyP, keyR, row_start, cnt, eidx,
                                   cw, cb, w1, bb1, w2, bb2, out);
}